// Round 8
// baseline (701.619 us; speedup 1.0000x reference)
//
#include <hip/hip_runtime.h>
#include <hip/hip_bf16.h>
#include <math.h>

typedef __attribute__((ext_vector_type(8))) short bf16x8;
typedef __attribute__((ext_vector_type(4))) float f32x4;

#define NB 512          // persistent grid: 2 blocks/CU on 256 CUs, guaranteed co-resident
#define NGRP 8          // barrier tree groups (64 blocks each)

__device__ __forceinline__ float sigmoidf_(float x){ return 1.f/(1.f + expf(-x)); }
__device__ __forceinline__ short f2bf(float x){
    union { __hip_bfloat16 h; short s; } u; u.h = __float2bfloat16(x); return u.s;
}
__device__ __forceinline__ float bf2f(short s){
    union { unsigned u; float f; } v; v.u = ((unsigned)(unsigned short)s) << 16; return v.f;
}

// ---------------- device-wide tree barrier (agent scope, sense via generation) -------
// bar[0]=generation, bar[1]=root count, bar[2..9]=group counts. Zeroed per launch.
__device__ __forceinline__ void gbar(int* bar)
{
    __syncthreads();
    if (threadIdx.x == 0) {
        int gen = __hip_atomic_load(&bar[0], __ATOMIC_RELAXED, __HIP_MEMORY_SCOPE_AGENT);
        int g = blockIdx.x >> 6;                 // 8 groups of 64
        int a = __hip_atomic_fetch_add(&bar[2+g], 1, __ATOMIC_ACQ_REL, __HIP_MEMORY_SCOPE_AGENT);
        if (a == 63) {
            __hip_atomic_store(&bar[2+g], 0, __ATOMIC_RELAXED, __HIP_MEMORY_SCOPE_AGENT);
            int r = __hip_atomic_fetch_add(&bar[1], 1, __ATOMIC_ACQ_REL, __HIP_MEMORY_SCOPE_AGENT);
            if (r == NGRP-1) {
                __hip_atomic_store(&bar[1], 0, __ATOMIC_RELAXED, __HIP_MEMORY_SCOPE_AGENT);
                __hip_atomic_fetch_add(&bar[0], 1, __ATOMIC_RELEASE, __HIP_MEMORY_SCOPE_AGENT);
            }
        }
        while (__hip_atomic_load(&bar[0], __ATOMIC_RELAXED, __HIP_MEMORY_SCOPE_AGENT) == gen)
            __builtin_amdgcn_s_sleep(2);
        (void)__hip_atomic_load(&bar[0], __ATOMIC_ACQUIRE, __HIP_MEMORY_SCOPE_AGENT);
    }
    __syncthreads();
}

// ---------------- MFMA cores (byte-identical math to R5/R7) --------------------------
template<int TRANS, int BIAS>
__device__ void mm_core(
    const short* __restrict__ Abf, const float* __restrict__ W,
    const float* __restrict__ bias, float* __restrict__ outP,
    int K, int Kp, int N, int ks0, int ks1, int nblk)
{
    const int lane = threadIdx.x & 63;
    const int wave = threadIdx.x >> 6;
    const int l16  = lane & 15;
    const int lg   = lane >> 4;
    const int n    = nblk*64 + wave*16 + l16;
    const int nc   = min(n, N-1);

    f32x4 acc[4];
#pragma unroll
    for (int mt = 0; mt < 4; mt++) acc[mt] = f32x4{0.f,0.f,0.f,0.f};

    for (int ks = ks0; ks < ks1; ks++) {
        const int kl = ks*32 + lg*8;
        const short* ap = Abf + (long)l16*Kp + kl;
        bf16x8 a0 = *(const bf16x8*)(ap);
        bf16x8 a1 = *(const bf16x8*)(ap + (long)16*Kp);
        bf16x8 a2 = *(const bf16x8*)(ap + (long)32*Kp);
        bf16x8 a3 = *(const bf16x8*)(ap + (long)48*Kp);
        float wv[8];
        if (TRANS) {
            const float* wr = W + (long)nc*K;
            if (kl + 8 <= K) {
                float4 f0 = *(const float4*)(wr + kl);
                float4 f1 = *(const float4*)(wr + kl + 4);
                wv[0]=f0.x; wv[1]=f0.y; wv[2]=f0.z; wv[3]=f0.w;
                wv[4]=f1.x; wv[5]=f1.y; wv[6]=f1.z; wv[7]=f1.w;
            } else {
#pragma unroll
                for (int j=0;j<8;j++) wv[j] = wr[min(kl+j, K-1)];
            }
        } else {
            const float* wk = W + (long)kl*(long)N + nc;
            if (kl + 8 <= K) {
#pragma unroll
                for (int j=0;j<8;j++) wv[j] = wk[(long)j*N];
            } else {
#pragma unroll
                for (int j=0;j<8;j++) wv[j] = (kl+j < K) ? wk[(long)j*N] : 0.f;
            }
        }
        bf16x8 b;
#pragma unroll
        for (int j=0;j<8;j++) b[j] = f2bf(wv[j]);

        acc[0] = __builtin_amdgcn_mfma_f32_16x16x32_bf16(a0, b, acc[0], 0, 0, 0);
        acc[1] = __builtin_amdgcn_mfma_f32_16x16x32_bf16(a1, b, acc[1], 0, 0, 0);
        acc[2] = __builtin_amdgcn_mfma_f32_16x16x32_bf16(a2, b, acc[2], 0, 0, 0);
        acc[3] = __builtin_amdgcn_mfma_f32_16x16x32_bf16(a3, b, acc[3], 0, 0, 0);
    }

    if (n < N) {
        const float bv = BIAS ? bias[n] : 0.f;
#pragma unroll
        for (int mt = 0; mt < 4; mt++) {
#pragma unroll
            for (int q = 0; q < 4; q++) {
                int row = mt*16 + lg*4 + q;
                outP[(long)row*N + n] = acc[mt][q] + bv;
            }
        }
    }
}

template<int TRANS>
__device__ void mm_core4(
    const short* __restrict__ Ahi, const short* __restrict__ Alo,
    const float* __restrict__ W, float* __restrict__ outP,
    int K, int Kp, int N, int ks0, int ks1, int nblk)
{
    const int lane = threadIdx.x & 63;
    const int wave = threadIdx.x >> 6;
    const int l16  = lane & 15;
    const int lg   = lane >> 4;
    const int n    = nblk*64 + wave*16 + l16;
    const int nc   = min(n, N-1);

    f32x4 acc[4];
#pragma unroll
    for (int mt = 0; mt < 4; mt++) acc[mt] = f32x4{0.f,0.f,0.f,0.f};

    for (int ks = ks0; ks < ks1; ks++) {
        const int kl = ks*32 + lg*8;
        const long o0 = (long)l16*Kp + kl;
        bf16x8 ah0 = *(const bf16x8*)(Ahi + o0);
        bf16x8 ah1 = *(const bf16x8*)(Ahi + o0 + (long)16*Kp);
        bf16x8 ah2 = *(const bf16x8*)(Ahi + o0 + (long)32*Kp);
        bf16x8 ah3 = *(const bf16x8*)(Ahi + o0 + (long)48*Kp);
        bf16x8 al0 = *(const bf16x8*)(Alo + o0);
        bf16x8 al1 = *(const bf16x8*)(Alo + o0 + (long)16*Kp);
        bf16x8 al2 = *(const bf16x8*)(Alo + o0 + (long)32*Kp);
        bf16x8 al3 = *(const bf16x8*)(Alo + o0 + (long)48*Kp);
        float wv[8];
        if (TRANS) {
            const float* wr = W + (long)nc*K;
            if (kl + 8 <= K) {
                float4 f0 = *(const float4*)(wr + kl);
                float4 f1 = *(const float4*)(wr + kl + 4);
                wv[0]=f0.x; wv[1]=f0.y; wv[2]=f0.z; wv[3]=f0.w;
                wv[4]=f1.x; wv[5]=f1.y; wv[6]=f1.z; wv[7]=f1.w;
            } else {
#pragma unroll
                for (int j=0;j<8;j++) wv[j] = wr[min(kl+j, K-1)];
            }
        } else {
            const float* wk = W + (long)kl*(long)N + nc;
            if (kl + 8 <= K) {
#pragma unroll
                for (int j=0;j<8;j++) wv[j] = wk[(long)j*N];
            } else {
#pragma unroll
                for (int j=0;j<8;j++) wv[j] = (kl+j < K) ? wk[(long)j*N] : 0.f;
            }
        }
        bf16x8 bh, bl;
#pragma unroll
        for (int j=0;j<8;j++) {
            short h = f2bf(wv[j]);
            bh[j] = h;
            bl[j] = f2bf(wv[j] - bf2f(h));
        }
        acc[0] = __builtin_amdgcn_mfma_f32_16x16x32_bf16(ah0, bh, acc[0], 0, 0, 0);
        acc[1] = __builtin_amdgcn_mfma_f32_16x16x32_bf16(ah1, bh, acc[1], 0, 0, 0);
        acc[2] = __builtin_amdgcn_mfma_f32_16x16x32_bf16(ah2, bh, acc[2], 0, 0, 0);
        acc[3] = __builtin_amdgcn_mfma_f32_16x16x32_bf16(ah3, bh, acc[3], 0, 0, 0);
        acc[0] = __builtin_amdgcn_mfma_f32_16x16x32_bf16(ah0, bl, acc[0], 0, 0, 0);
        acc[1] = __builtin_amdgcn_mfma_f32_16x16x32_bf16(ah1, bl, acc[1], 0, 0, 0);
        acc[2] = __builtin_amdgcn_mfma_f32_16x16x32_bf16(ah2, bl, acc[2], 0, 0, 0);
        acc[3] = __builtin_amdgcn_mfma_f32_16x16x32_bf16(ah3, bl, acc[3], 0, 0, 0);
        acc[0] = __builtin_amdgcn_mfma_f32_16x16x32_bf16(al0, bh, acc[0], 0, 0, 0);
        acc[1] = __builtin_amdgcn_mfma_f32_16x16x32_bf16(al1, bh, acc[1], 0, 0, 0);
        acc[2] = __builtin_amdgcn_mfma_f32_16x16x32_bf16(al2, bh, acc[2], 0, 0, 0);
        acc[3] = __builtin_amdgcn_mfma_f32_16x16x32_bf16(al3, bh, acc[3], 0, 0, 0);
        acc[0] = __builtin_amdgcn_mfma_f32_16x16x32_bf16(al0, bl, acc[0], 0, 0, 0);
        acc[1] = __builtin_amdgcn_mfma_f32_16x16x32_bf16(al1, bl, acc[1], 0, 0, 0);
        acc[2] = __builtin_amdgcn_mfma_f32_16x16x32_bf16(al2, bl, acc[2], 0, 0, 0);
        acc[3] = __builtin_amdgcn_mfma_f32_16x16x32_bf16(al3, bl, acc[3], 0, 0, 0);
    }

    if (n < N) {
#pragma unroll
        for (int mt = 0; mt < 4; mt++) {
#pragma unroll
            for (int q = 0; q < 4; q++) {
                int row = mt*16 + lg*4 + q;
                outP[(long)row*N + n] = acc[mt][q];
            }
        }
    }
}

// =====================================================================================
// THE persistent mega kernel: 12 phases, 11 device-wide barriers, zero launch gaps.
// =====================================================================================
__global__ __launch_bounds__(256, 2) void k_mega(
    const int* __restrict__ dec_in, const float* __restrict__ attn_h,
    const float* __restrict__ enc,  const int* __restrict__ lengths,
    const float* __restrict__ h0,   const float* __restrict__ embed,
    const float* __restrict__ w_ih0, const float* __restrict__ w_hh0,
    const float* __restrict__ b_ih0, const float* __restrict__ b_hh0,
    const float* __restrict__ w_ih1, const float* __restrict__ w_hh1,
    const float* __restrict__ b_ih1, const float* __restrict__ b_hh1,
    const float* __restrict__ Wp_w, const float* __restrict__ Wp_b,
    const float* __restrict__ Vp_w, const float* __restrict__ Vp_b,
    const float* __restrict__ Wc_w, const float* __restrict__ Wc_b,
    const float* __restrict__ out_w, const float* __restrict__ out_b,
    float* __restrict__ y,
    short* xhi, short* xlo, short* h0hi, short* h0lo,
    short* x1hi, short* x1lo, short* hthi, short* htlo,
    short* catbf, short* habf, float* ht,
    float* PgiL0, float* PghL0, float* PgiL1, float* PghL1,
    float* Pwp, float* Pwc, float* partS, float* lse, int* bar)
{
    // static LDS (max over phases): attn arrays + out/merge scratch
    __shared__ float sm_hts[1000];
    __shared__ float sm_hs[11][1000];
    __shared__ float sm_aa[16];
    __shared__ float sm_red[4];
    __shared__ int   sm_p[2];
    __shared__ float sm_ps[256];

    const int tid  = threadIdx.x;
    const int gtid = blockIdx.x*256 + tid;
    const int lane = tid & 63, wave = tid >> 6;

    // ---------------- P0: prep (hi/lo bf16 A matrices + zero tails) ----------------
    for (int i = gtid; i < 221184; i += NB*256) {
        int r = i;
        if (r < 64*1312) {
            int b = r / 1312, k = r % 1312;
            float v = 0.f;
            if (k < 300)       v = embed[(long)dec_in[b]*300 + k];
            else if (k < 1300) v = attn_h[b*1000 + (k-300)];
            short h = f2bf(v);
            xhi[r] = h; xlo[r] = f2bf(v - bf2f(h));
            continue;
        }
        r -= 64*1312;
        if (r < 4*64*512) {
            int k = r & 511, b = (r >> 9) & 63, d = r >> 15;
            float v = (k < 500) ? h0[((long)d*64 + b)*500 + k] : 0.f;
            short h = f2bf(v);
            h0hi[r] = h; h0lo[r] = f2bf(v - bf2f(h));
            continue;
        }
        r -= 4*64*512;
        if (r < 1536) {
            int b = r/24; long o = (long)b*1024 + 1000 + r%24;
            x1hi[o]=0; x1lo[o]=0; hthi[o]=0; htlo[o]=0; continue;
        }
        r -= 1536;
        if (r < 1536) { int b = r/24; habf[(long)b*1024 + 1000 + r%24] = 0; continue; }
        r -= 1536;
        { int b = r/48; catbf[(long)b*2048 + 2000 + r%48] = 0; }
    }
    gbar(bar);

    // ---------------- P1: GRU GEMMs independent of x1: L0ih, L0hh, L1hh ------------
    for (int it = blockIdx.x; it < 432; it += NB) {
        if (it < 240) {                       // L0 ih: K=1300 Kp=1312, 41 ksteps, S=5x9
            int z = it / 120, rem = it % 120, s = rem / 24, nblk = rem % 24;
            mm_core4<1>(xhi, xlo, w_ih0 + (long)z*1500*1300,
                        PgiL0 + (long)(z*5 + s)*96000, 1300, 1312, 1500,
                        s*9, min(41, s*9+9), nblk);
        } else if (it < 336) {                // L0 hh: K=500 Kp=512, 16 ksteps, S=2x8
            int t = it - 240, d = t / 48, rem = t % 48, s = rem / 24, nblk = rem % 24;
            const long ao = (long)(0*2 + d)*64*512;
            mm_core4<1>(h0hi + ao, h0lo + ao, w_hh0 + (long)d*1500*500,
                        PghL0 + (long)(d*2 + s)*96000, 500, 512, 1500,
                        s*8, min(16, s*8+8), nblk);
        } else {                              // L1 hh
            int t = it - 336, d = t / 48, rem = t % 48, s = rem / 24, nblk = rem % 24;
            const long ao = (long)(1*2 + d)*64*512;
            mm_core4<1>(h0hi + ao, h0lo + ao, w_hh1 + (long)d*1500*500,
                        PghL1 + (long)(d*2 + s)*96000, 500, 512, 1500,
                        s*8, min(16, s*8+8), nblk);
        }
    }
    gbar(bar);

    // ---------------- P2: gates L0 -> x1 (hi/lo) -----------------------------------
    for (int i = gtid; i < 64000; i += NB*256) {
        int d = i / 32000, r = i % 32000, b = r / 500, q = r % 500;
        long base = (long)b*1500 + q;
        float g0 = b_ih0[d*1500 + q], g1 = b_ih0[d*1500 + 500 + q], g2 = b_ih0[d*1500 + 1000 + q];
        for (int s = 0; s < 5; s++) {
            const float* P = PgiL0 + (long)(d*5 + s)*96000 + base;
            g0 += P[0]; g1 += P[500]; g2 += P[1000];
        }
        float h0v = b_hh0[d*1500 + q], h1v = b_hh0[d*1500 + 500 + q], h2v = b_hh0[d*1500 + 1000 + q];
        for (int s = 0; s < 2; s++) {
            const float* P = PghL0 + (long)(d*2 + s)*96000 + base;
            h0v += P[0]; h1v += P[500]; h2v += P[1000];
        }
        float hp = h0[((long)d*64 + b)*500 + q];
        float rr = sigmoidf_(g0 + h0v);
        float zz = sigmoidf_(g1 + h1v);
        float nn = tanhf(g2 + rr*h2v);
        float o = (1.f - zz)*nn + zz*hp;
        long oo = (long)b*1024 + d*500 + q;
        short h = f2bf(o);
        x1hi[oo] = h; x1lo[oo] = f2bf(o - bf2f(h));
    }
    gbar(bar);

    // ---------------- P3: L1 ih GEMM (needs x1) -------------------------------------
    for (int it = blockIdx.x; it < 192; it += NB) {
        int z = it / 96, rem = it % 96, s = rem / 24, nblk = rem % 24;
        mm_core4<1>(x1hi, x1lo, w_ih1 + (long)z*1500*1000,
                    PgiL1 + (long)(z*4 + s)*96000, 1000, 1024, 1500,
                    s*8, min(32, s*8+8), nblk);
    }
    gbar(bar);

    // ---------------- P4: gates L1 -> ht (hi/lo + fp32) -----------------------------
    for (int i = gtid; i < 64000; i += NB*256) {
        int d = i / 32000, r = i % 32000, b = r / 500, q = r % 500;
        long base = (long)b*1500 + q;
        float g0 = b_ih1[d*1500 + q], g1 = b_ih1[d*1500 + 500 + q], g2 = b_ih1[d*1500 + 1000 + q];
        for (int s = 0; s < 4; s++) {
            const float* P = PgiL1 + (long)(d*4 + s)*96000 + base;
            g0 += P[0]; g1 += P[500]; g2 += P[1000];
        }
        float h0v = b_hh1[d*1500 + q], h1v = b_hh1[d*1500 + 500 + q], h2v = b_hh1[d*1500 + 1000 + q];
        for (int s = 0; s < 2; s++) {
            const float* P = PghL1 + (long)(d*2 + s)*96000 + base;
            h0v += P[0]; h1v += P[500]; h2v += P[1000];
        }
        float hp = h0[((long)(2 + d)*64 + b)*500 + q];
        float rr = sigmoidf_(g0 + h0v);
        float zz = sigmoidf_(g1 + h1v);
        float nn = tanhf(g2 + rr*h2v);
        float o = (1.f - zz)*nn + zz*hp;
        long oo = (long)b*1024 + d*500 + q;
        short h = f2bf(o);
        hthi[oo] = h; htlo[oo] = f2bf(o - bf2f(h));
        ht[(long)b*1000 + d*500 + q] = o;
    }
    gbar(bar);

    // ---------------- P5: Wp GEMM (split-precision, S=8x4) --------------------------
    for (int it = blockIdx.x; it < 128; it += NB) {
        int s = it / 16, nblk = it % 16;
        mm_core4<0>(hthi, htlo, Wp_w, Pwp + (long)s*64000, 1000, 1024, 1000,
                    s*4, min(32, s*4+4), nblk);
    }
    gbar(bar);

    // ---------------- P6: attention + fused pt -> catbf -----------------------------
    for (int b = blockIdx.x; b < 64; b += NB) {
        float ps = 0.f;
        for (int j = tid; j < 1000; j += 256) {
            float v = Wp_b[j];
#pragma unroll
            for (int s = 0; s < 8; s++) v += Pwp[(long)s*64000 + (long)b*1000 + j];
            ps += tanhf(v) * Vp_w[j];
        }
        for (int off = 32; off; off >>= 1) ps += __shfl_down(ps, off);
        if (lane == 0) sm_red[wave] = ps;
        for (int h = tid; h < 1000; h += 256) sm_hts[h] = ht[b*1000 + h];
        __syncthreads();
        if (tid == 0) {
            float tot = sm_red[0] + sm_red[1] + sm_red[2] + sm_red[3];
            float s = 1.f/(1.f + expf(-(tot + Vp_b[0])));
            int len = lengths[b];
            int pt = (int)((float)len * s);
            sm_p[0] = min(len - 5, max(0, pt - 5));
            sm_p[1] = min(len, pt + 6);
        }
        __syncthreads();
        int p0 = sm_p[0], p1 = sm_p[1];
        for (int k = 0; k < 11; k++) {
            int row = min(p0 + k, 1023);
            const float* er = enc + ((long)b*1024 + row)*1000;
            for (int h = tid; h < 1000; h += 256) sm_hs[k][h] = er[h];
        }
        __syncthreads();
        for (int k = wave; k < 11; k += 4) {
            float d = 0.f;
            for (int h = lane; h < 1000; h += 64) d += sm_hts[h]*sm_hs[k][h];
            for (int off = 32; off; off >>= 1) d += __shfl_down(d, off);
            if (lane == 0) sm_aa[k] = d;
        }
        __syncthreads();
        if (tid == 0) {
            int nv = min(p1 - p0, 11);
            float m = -1e30f;
            for (int k = 0; k < nv; k++) m = fmaxf(m, sm_aa[k]);
            float ssum = 0.f;
            for (int k = 0; k < 11; k++) { float e = (k < nv) ? expf(sm_aa[k]-m) : 0.f; sm_aa[k] = e; ssum += e; }
            float inv = 1.f/ssum;
            for (int k = 0; k < 11; k++) sm_aa[k] *= inv;
        }
        __syncthreads();
        for (int h = tid; h < 1000; h += 256) {
            float c = 0.f;
#pragma unroll
            for (int k = 0; k < 11; k++) c += sm_aa[k]*sm_hs[k][h];
            catbf[(long)b*2048 + h]        = f2bf(c);
            catbf[(long)b*2048 + 1000 + h] = f2bf(sm_hts[h]);
        }
        __syncthreads();
    }
    gbar(bar);

    // ---------------- P7: Wc GEMM (single bf16, S=8x8) ------------------------------
    for (int it = blockIdx.x; it < 128; it += NB) {
        int s = it / 16, nblk = it % 16;
        mm_core<0,0>(catbf, Wc_w, nullptr, Pwc + (long)s*64000, 2000, 2048, 1000,
                     s*8, s*8+8, nblk);
    }
    gbar(bar);

    // ---------------- P8: hattn combine + tanh -> habf -------------------------------
    for (int i = gtid; i < 64000; i += NB*256) {
        int b = i / 1000, nn = i % 1000;
        float v = Wc_b[nn];
        for (int s = 0; s < 8; s++) v += Pwc[(long)s*64000 + i];
        habf[(long)b*1024 + nn] = f2bf(tanhf(v));
    }
    gbar(bar);

    // ---------------- P9: output projection + partS epilogue ------------------------
    for (int nblk = blockIdx.x; nblk < 786; nblk += NB) {
        const int N = 50257, K = 1000, Kp = 1024;
        const int l16 = lane & 15, lg = lane >> 4;
        const int n   = nblk*64 + wave*16 + l16;
        const bool ok = n < N;
        const int nc  = ok ? n : (N-1);

        f32x4 acc[4];
#pragma unroll
        for (int mt = 0; mt < 4; mt++) acc[mt] = f32x4{0.f,0.f,0.f,0.f};

        for (int ks = 0; ks < 32; ks++) {
            const int kl = ks*32 + lg*8;
            const short* ap = habf + (long)l16*Kp + kl;
            bf16x8 a0 = *(const bf16x8*)(ap);
            bf16x8 a1 = *(const bf16x8*)(ap + (long)16*Kp);
            bf16x8 a2 = *(const bf16x8*)(ap + (long)32*Kp);
            bf16x8 a3 = *(const bf16x8*)(ap + (long)48*Kp);
            float wv[8];
            const float* wk = out_w + (long)kl*(long)N + nc;
            if (kl + 8 <= K) {
#pragma unroll
                for (int j=0;j<8;j++) wv[j] = wk[(long)j*N];
            } else {
#pragma unroll
                for (int j=0;j<8;j++) wv[j] = (kl+j < K) ? wk[(long)j*N] : 0.f;
            }
            bf16x8 b;
#pragma unroll
            for (int j=0;j<8;j++) b[j] = f2bf(wv[j]);
            acc[0] = __builtin_amdgcn_mfma_f32_16x16x32_bf16(a0, b, acc[0], 0, 0, 0);
            acc[1] = __builtin_amdgcn_mfma_f32_16x16x32_bf16(a1, b, acc[1], 0, 0, 0);
            acc[2] = __builtin_amdgcn_mfma_f32_16x16x32_bf16(a2, b, acc[2], 0, 0, 0);
            acc[3] = __builtin_amdgcn_mfma_f32_16x16x32_bf16(a3, b, acc[3], 0, 0, 0);
        }

        const float bv = ok ? out_b[n] : 0.f;
#pragma unroll
        for (int mt = 0; mt < 4; mt++) {
#pragma unroll
            for (int q = 0; q < 4; q++) {
                int row = mt*16 + lg*4 + q;
                float v = acc[mt][q] + bv;
                if (ok) y[(long)row*N + n] = v;
                float e = ok ? expf(v) : 0.f;
                e += __shfl_xor(e, 1);
                e += __shfl_xor(e, 2);
                e += __shfl_xor(e, 4);
                e += __shfl_xor(e, 8);
                if (l16 == 0) sm_ps[wave*64 + row] = e;
            }
        }
        __syncthreads();
        if (tid < 64)
            partS[(long)tid*786 + nblk] = sm_ps[tid] + sm_ps[64+tid] + sm_ps[128+tid] + sm_ps[192+tid];
        __syncthreads();
    }
    gbar(bar);

    // ---------------- P10: merge partS -> lse ---------------------------------------
    for (int row = blockIdx.x; row < 64; row += NB) {
        float s = 0.f;
        for (int p = tid; p < 786; p += 256) s += partS[(long)row*786 + p];
        for (int off = 32; off; off >>= 1) s += __shfl_down(s, off);
        if (lane == 0) sm_red[wave] = s;
        __syncthreads();
        if (tid == 0) lse[row] = logf(sm_red[0] + sm_red[1] + sm_red[2] + sm_red[3]);
        __syncthreads();
    }
    gbar(bar);

    // ---------------- P11: subtract lse in place ------------------------------------
    for (int i = gtid; i < 64*50257; i += NB*256) {
        int b = i / 50257;
        y[i] -= lse[b];
    }
}

// =====================================================================================
extern "C" void kernel_launch(void* const* d_in, const int* in_sizes, int n_in,
                              void* d_out, int out_size, void* d_ws, size_t ws_size,
                              hipStream_t stream)
{
    const int*   dec_in  = (const int*)  d_in[0];
    const float* attn_h  = (const float*)d_in[1];
    const float* enc     = (const float*)d_in[2];
    // d_in[3] = mask0 (unused: m_w == valid within the window)
    const int*   lengths = (const int*)  d_in[4];
    const float* h0      = (const float*)d_in[5];
    const float* embed   = (const float*)d_in[6];
    const float* w_ih0   = (const float*)d_in[7];
    const float* w_hh0   = (const float*)d_in[8];
    const float* b_ih0   = (const float*)d_in[9];
    const float* b_hh0   = (const float*)d_in[10];
    const float* w_ih1   = (const float*)d_in[11];
    const float* w_hh1   = (const float*)d_in[12];
    const float* b_ih1   = (const float*)d_in[13];
    const float* b_hh1   = (const float*)d_in[14];
    const float* Wp_w    = (const float*)d_in[15];
    const float* Wp_b    = (const float*)d_in[16];
    const float* Vp_w    = (const float*)d_in[17];
    const float* Vp_b    = (const float*)d_in[18];
    const float* Wc_w    = (const float*)d_in[19];
    const float* Wc_b    = (const float*)d_in[20];
    const float* out_w   = (const float*)d_in[21];
    const float* out_b   = (const float*)d_in[22];
    float* y = (float*)d_out;

    // ---- workspace layout (floats), verified non-overlapping ----
    float* ws = (float*)d_ws;
    short* xhi   = (short*)(ws + 0);         // 41,984 fl -> 42,000
    short* xlo   = (short*)(ws + 42000);
    short* h0hi  = (short*)(ws + 84000);     // 65,536 fl -> 65,600
    short* h0lo  = (short*)(ws + 149600);
    short* x1hi  = (short*)(ws + 215200);    // 32,768 fl -> 32,800
    short* x1lo  = (short*)(ws + 248000);
    short* hthi  = (short*)(ws + 280800);
    short* htlo  = (short*)(ws + 313600);
    short* catbf = (short*)(ws + 346400);    // 65,536 fl -> 65,600
    short* habf  = (short*)(ws + 412000);    // 32,768 fl -> 32,800
    float* ht    = ws + 444800;              // 64,000
    float* PgiL0 = ws + 508800;              // 2*5*96000 = 960,000
    float* PghL0 = ws + 1468800;             // 2*2*96000 = 384,000
    float* PgiL1 = ws + 1852800;             // 2*4*96000 = 768,000
    float* PghL1 = ws + 2620800;             // 384,000
    float* Pwp   = ws + 3004800;             // 8*64000 = 512,000
    float* Pwc   = ws + 3516800;             // 512,000
    float* partS = ws + 4028800;             // 50,304 -> 50,400
    float* lse   = ws + 4079200;             // 64
    int*   bar   = (int*)(ws + 4079264);     // 16 ints (gen, root, 8 groups)

    // zero the barrier state every call (ws is poisoned 0xAA before timing)
    hipMemsetAsync(bar, 0, 16*sizeof(int), stream);

    k_mega<<<dim3(NB), dim3(256), 0, stream>>>(
        dec_in, attn_h, enc, lengths, h0, embed,
        w_ih0, w_hh0, b_ih0, b_hh0, w_ih1, w_hh1, b_ih1, b_hh1,
        Wp_w, Wp_b, Vp_w, Vp_b, Wc_w, Wc_b, out_w, out_b, y,
        xhi, xlo, h0hi, h0lo, x1hi, x1lo, hthi, htlo,
        catbf, habf, ht, PgiL0, PghL0, PgiL1, PghL1,
        Pwp, Pwc, partS, lse, bar);
}

// Round 9
// 651.871 us; speedup vs baseline: 1.0763x; 1.0763x over previous
//
#include <hip/hip_runtime.h>
#include <hip/hip_bf16.h>
#include <math.h>

typedef __attribute__((ext_vector_type(8))) short bf16x8;
typedef __attribute__((ext_vector_type(4))) float f32x4;

#define NB 1024         // persistent grid: 4 blocks/CU on 256 CUs (VGPR<=128, LDS ~6KB)
#define NGRP 16         // barrier groups of 64 blocks, padded cachelines

__device__ __forceinline__ float sigmoidf_(float x){ return 1.f/(1.f + expf(-x)); }
__device__ __forceinline__ short f2bf(float x){
    union { __hip_bfloat16 h; short s; } u; u.h = __float2bfloat16(x); return u.s;
}
__device__ __forceinline__ float bf2f(short s){
    union { unsigned u; float f; } v; v.u = ((unsigned)(unsigned short)s) << 16; return v.f;
}

// ---------------- hierarchical device barrier, contention-spread -----------------------
// bar[g*16]           : group arrive counters (16 groups, 64B apart)
// bar[256]            : root counter
// bar[272 + g*16]     : per-group generation words (spun on; 64 spinners/line max)
__device__ __forceinline__ void gbar(int* bar)
{
    __syncthreads();
    if (threadIdx.x == 0) {
        const int g = blockIdx.x >> 6;
        int* gcnt = &bar[g*16];
        int* ggen = &bar[272 + g*16];
        int mygen = __hip_atomic_load(ggen, __ATOMIC_RELAXED, __HIP_MEMORY_SCOPE_AGENT);
        int a = __hip_atomic_fetch_add(gcnt, 1, __ATOMIC_ACQ_REL, __HIP_MEMORY_SCOPE_AGENT);
        if (a == 63) {
            __hip_atomic_store(gcnt, 0, __ATOMIC_RELAXED, __HIP_MEMORY_SCOPE_AGENT);
            int r = __hip_atomic_fetch_add(&bar[256], 1, __ATOMIC_ACQ_REL, __HIP_MEMORY_SCOPE_AGENT);
            if (r == NGRP-1) {
                __hip_atomic_store(&bar[256], 0, __ATOMIC_RELAXED, __HIP_MEMORY_SCOPE_AGENT);
#pragma unroll
                for (int i = 0; i < NGRP; i++)
                    __hip_atomic_store(&bar[272 + i*16], mygen + 1, __ATOMIC_RELEASE, __HIP_MEMORY_SCOPE_AGENT);
            }
        }
        while (__hip_atomic_load(ggen, __ATOMIC_RELAXED, __HIP_MEMORY_SCOPE_AGENT) == mygen)
            __builtin_amdgcn_s_sleep(8);
        (void)__hip_atomic_load(ggen, __ATOMIC_ACQUIRE, __HIP_MEMORY_SCOPE_AGENT);
    }
    __syncthreads();
}

// ---------------- MFMA cores (byte-identical math to R5) -----------------------------
template<int TRANS, int BIAS>
__device__ void mm_core(
    const short* __restrict__ Abf, const float* __restrict__ W,
    const float* __restrict__ bias, float* __restrict__ outP,
    int K, int Kp, int N, int ks0, int ks1, int nblk)
{
    const int lane = threadIdx.x & 63;
    const int wave = threadIdx.x >> 6;
    const int l16  = lane & 15;
    const int lg   = lane >> 4;
    const int n    = nblk*64 + wave*16 + l16;
    const int nc   = min(n, N-1);

    f32x4 acc[4];
#pragma unroll
    for (int mt = 0; mt < 4; mt++) acc[mt] = f32x4{0.f,0.f,0.f,0.f};

    for (int ks = ks0; ks < ks1; ks++) {
        const int kl = ks*32 + lg*8;
        const short* ap = Abf + (long)l16*Kp + kl;
        bf16x8 a0 = *(const bf16x8*)(ap);
        bf16x8 a1 = *(const bf16x8*)(ap + (long)16*Kp);
        bf16x8 a2 = *(const bf16x8*)(ap + (long)32*Kp);
        bf16x8 a3 = *(const bf16x8*)(ap + (long)48*Kp);
        float wv[8];
        if (TRANS) {
            const float* wr = W + (long)nc*K;
            if (kl + 8 <= K) {
                float4 f0 = *(const float4*)(wr + kl);
                float4 f1 = *(const float4*)(wr + kl + 4);
                wv[0]=f0.x; wv[1]=f0.y; wv[2]=f0.z; wv[3]=f0.w;
                wv[4]=f1.x; wv[5]=f1.y; wv[6]=f1.z; wv[7]=f1.w;
            } else {
#pragma unroll
                for (int j=0;j<8;j++) wv[j] = wr[min(kl+j, K-1)];
            }
        } else {
            const float* wk = W + (long)kl*(long)N + nc;
            if (kl + 8 <= K) {
#pragma unroll
                for (int j=0;j<8;j++) wv[j] = wk[(long)j*N];
            } else {
#pragma unroll
                for (int j=0;j<8;j++) wv[j] = (kl+j < K) ? wk[(long)j*N] : 0.f;
            }
        }
        bf16x8 b;
#pragma unroll
        for (int j=0;j<8;j++) b[j] = f2bf(wv[j]);

        acc[0] = __builtin_amdgcn_mfma_f32_16x16x32_bf16(a0, b, acc[0], 0, 0, 0);
        acc[1] = __builtin_amdgcn_mfma_f32_16x16x32_bf16(a1, b, acc[1], 0, 0, 0);
        acc[2] = __builtin_amdgcn_mfma_f32_16x16x32_bf16(a2, b, acc[2], 0, 0, 0);
        acc[3] = __builtin_amdgcn_mfma_f32_16x16x32_bf16(a3, b, acc[3], 0, 0, 0);
    }

    if (n < N) {
        const float bv = BIAS ? bias[n] : 0.f;
#pragma unroll
        for (int mt = 0; mt < 4; mt++) {
#pragma unroll
            for (int q = 0; q < 4; q++) {
                int row = mt*16 + lg*4 + q;
                outP[(long)row*N + n] = acc[mt][q] + bv;
            }
        }
    }
}

template<int TRANS>
__device__ void mm_core4(
    const short* __restrict__ Ahi, const short* __restrict__ Alo,
    const float* __restrict__ W, float* __restrict__ outP,
    int K, int Kp, int N, int ks0, int ks1, int nblk)
{
    const int lane = threadIdx.x & 63;
    const int wave = threadIdx.x >> 6;
    const int l16  = lane & 15;
    const int lg   = lane >> 4;
    const int n    = nblk*64 + wave*16 + l16;
    const int nc   = min(n, N-1);

    f32x4 acc[4];
#pragma unroll
    for (int mt = 0; mt < 4; mt++) acc[mt] = f32x4{0.f,0.f,0.f,0.f};

    for (int ks = ks0; ks < ks1; ks++) {
        const int kl = ks*32 + lg*8;
        const long o0 = (long)l16*Kp + kl;
        bf16x8 ah0 = *(const bf16x8*)(Ahi + o0);
        bf16x8 ah1 = *(const bf16x8*)(Ahi + o0 + (long)16*Kp);
        bf16x8 ah2 = *(const bf16x8*)(Ahi + o0 + (long)32*Kp);
        bf16x8 ah3 = *(const bf16x8*)(Ahi + o0 + (long)48*Kp);
        bf16x8 al0 = *(const bf16x8*)(Alo + o0);
        bf16x8 al1 = *(const bf16x8*)(Alo + o0 + (long)16*Kp);
        bf16x8 al2 = *(const bf16x8*)(Alo + o0 + (long)32*Kp);
        bf16x8 al3 = *(const bf16x8*)(Alo + o0 + (long)48*Kp);
        float wv[8];
        if (TRANS) {
            const float* wr = W + (long)nc*K;
            if (kl + 8 <= K) {
                float4 f0 = *(const float4*)(wr + kl);
                float4 f1 = *(const float4*)(wr + kl + 4);
                wv[0]=f0.x; wv[1]=f0.y; wv[2]=f0.z; wv[3]=f0.w;
                wv[4]=f1.x; wv[5]=f1.y; wv[6]=f1.z; wv[7]=f1.w;
            } else {
#pragma unroll
                for (int j=0;j<8;j++) wv[j] = wr[min(kl+j, K-1)];
            }
        } else {
            const float* wk = W + (long)kl*(long)N + nc;
            if (kl + 8 <= K) {
#pragma unroll
                for (int j=0;j<8;j++) wv[j] = wk[(long)j*N];
            } else {
#pragma unroll
                for (int j=0;j<8;j++) wv[j] = (kl+j < K) ? wk[(long)j*N] : 0.f;
            }
        }
        bf16x8 bh, bl;
#pragma unroll
        for (int j=0;j<8;j++) {
            short h = f2bf(wv[j]);
            bh[j] = h;
            bl[j] = f2bf(wv[j] - bf2f(h));
        }
        acc[0] = __builtin_amdgcn_mfma_f32_16x16x32_bf16(ah0, bh, acc[0], 0, 0, 0);
        acc[1] = __builtin_amdgcn_mfma_f32_16x16x32_bf16(ah1, bh, acc[1], 0, 0, 0);
        acc[2] = __builtin_amdgcn_mfma_f32_16x16x32_bf16(ah2, bh, acc[2], 0, 0, 0);
        acc[3] = __builtin_amdgcn_mfma_f32_16x16x32_bf16(ah3, bh, acc[3], 0, 0, 0);
        acc[0] = __builtin_amdgcn_mfma_f32_16x16x32_bf16(ah0, bl, acc[0], 0, 0, 0);
        acc[1] = __builtin_amdgcn_mfma_f32_16x16x32_bf16(ah1, bl, acc[1], 0, 0, 0);
        acc[2] = __builtin_amdgcn_mfma_f32_16x16x32_bf16(ah2, bl, acc[2], 0, 0, 0);
        acc[3] = __builtin_amdgcn_mfma_f32_16x16x32_bf16(ah3, bl, acc[3], 0, 0, 0);
        acc[0] = __builtin_amdgcn_mfma_f32_16x16x32_bf16(al0, bh, acc[0], 0, 0, 0);
        acc[1] = __builtin_amdgcn_mfma_f32_16x16x32_bf16(al1, bh, acc[1], 0, 0, 0);
        acc[2] = __builtin_amdgcn_mfma_f32_16x16x32_bf16(al2, bh, acc[2], 0, 0, 0);
        acc[3] = __builtin_amdgcn_mfma_f32_16x16x32_bf16(al3, bh, acc[3], 0, 0, 0);
        acc[0] = __builtin_amdgcn_mfma_f32_16x16x32_bf16(al0, bl, acc[0], 0, 0, 0);
        acc[1] = __builtin_amdgcn_mfma_f32_16x16x32_bf16(al1, bl, acc[1], 0, 0, 0);
        acc[2] = __builtin_amdgcn_mfma_f32_16x16x32_bf16(al2, bl, acc[2], 0, 0, 0);
        acc[3] = __builtin_amdgcn_mfma_f32_16x16x32_bf16(al3, bl, acc[3], 0, 0, 0);
    }

    if (n < N) {
#pragma unroll
        for (int mt = 0; mt < 4; mt++) {
#pragma unroll
            for (int q = 0; q < 4; q++) {
                int row = mt*16 + lg*4 + q;
                outP[(long)row*N + n] = acc[mt][q];
            }
        }
    }
}

// =====================================================================================
// Persistent mega kernel v2: 12 phases, 11 low-contention barriers, 4 blocks/CU.
// =====================================================================================
__global__ __launch_bounds__(256, 4) void k_mega(
    const int* __restrict__ dec_in, const float* __restrict__ attn_h,
    const float* __restrict__ enc,  const int* __restrict__ lengths,
    const float* __restrict__ h0,   const float* __restrict__ embed,
    const float* __restrict__ w_ih0, const float* __restrict__ w_hh0,
    const float* __restrict__ b_ih0, const float* __restrict__ b_hh0,
    const float* __restrict__ w_ih1, const float* __restrict__ w_hh1,
    const float* __restrict__ b_ih1, const float* __restrict__ b_hh1,
    const float* __restrict__ Wp_w, const float* __restrict__ Wp_b,
    const float* __restrict__ Vp_w, const float* __restrict__ Vp_b,
    const float* __restrict__ Wc_w, const float* __restrict__ Wc_b,
    const float* __restrict__ out_w, const float* __restrict__ out_b,
    float* __restrict__ y,
    short* xhi, short* xlo, short* h0hi, short* h0lo,
    short* x1hi, short* x1lo, short* hthi, short* htlo,
    short* catbf, short* habf, float* ht,
    float* PgiL0, float* PghL0, float* PgiL1, float* PghL1,
    float* Pwp, float* Pwc, float* partS, float* lse, int* bar)
{
    __shared__ float sm_hts[1000];
    __shared__ float sm_aa[16];
    __shared__ float sm_red[4];
    __shared__ int   sm_p[2];
    __shared__ float sm_ps[256];

    const int tid  = threadIdx.x;
    const int gtid = blockIdx.x*256 + tid;
    const int lane = tid & 63, wave = tid >> 6;

    // ---------------- P0: prep (hi/lo bf16 A matrices + zero tails) ----------------
    for (int i = gtid; i < 221184; i += NB*256) {
        int r = i;
        if (r < 64*1312) {
            int b = r / 1312, k = r % 1312;
            float v = 0.f;
            if (k < 300)       v = embed[(long)dec_in[b]*300 + k];
            else if (k < 1300) v = attn_h[b*1000 + (k-300)];
            short h = f2bf(v);
            xhi[r] = h; xlo[r] = f2bf(v - bf2f(h));
            continue;
        }
        r -= 64*1312;
        if (r < 4*64*512) {
            int k = r & 511, b = (r >> 9) & 63, d = r >> 15;
            float v = (k < 500) ? h0[((long)d*64 + b)*500 + k] : 0.f;
            short h = f2bf(v);
            h0hi[r] = h; h0lo[r] = f2bf(v - bf2f(h));
            continue;
        }
        r -= 4*64*512;
        if (r < 1536) {
            int b = r/24; long o = (long)b*1024 + 1000 + r%24;
            x1hi[o]=0; x1lo[o]=0; hthi[o]=0; htlo[o]=0; continue;
        }
        r -= 1536;
        if (r < 1536) { int b = r/24; habf[(long)b*1024 + 1000 + r%24] = 0; continue; }
        r -= 1536;
        { int b = r/48; catbf[(long)b*2048 + 2000 + r%48] = 0; }
    }
    gbar(bar);

    // ---------------- P1: GEMMs not needing x1: L0ih(S=9x5), L0hh(S=4x4), L1hh ------
    for (int it = blockIdx.x; it < 816; it += NB) {
        if (it < 432) {
            int z = it / 216, rem = it % 216, s = rem / 24, nblk = rem % 24;
            mm_core4<1>(xhi, xlo, w_ih0 + (long)z*1500*1300,
                        PgiL0 + (long)(z*9 + s)*96000, 1300, 1312, 1500,
                        s*5, min(41, s*5+5), nblk);
        } else if (it < 624) {
            int t = it - 432, d = t / 96, rem = t % 96, s = rem / 24, nblk = rem % 24;
            const long ao = (long)d*32768;
            mm_core4<1>(h0hi + ao, h0lo + ao, w_hh0 + (long)d*750000,
                        PghL0 + (long)(d*4 + s)*96000, 500, 512, 1500,
                        s*4, min(16, s*4+4), nblk);
        } else {
            int t = it - 624, d = t / 96, rem = t % 96, s = rem / 24, nblk = rem % 24;
            const long ao = (long)(2 + d)*32768;
            mm_core4<1>(h0hi + ao, h0lo + ao, w_hh1 + (long)d*750000,
                        PghL1 + (long)(d*4 + s)*96000, 500, 512, 1500,
                        s*4, min(16, s*4+4), nblk);
        }
    }
    gbar(bar);

    // ---------------- P2: gates L0 -> x1 (hi/lo) -----------------------------------
    for (int i = gtid; i < 64000; i += NB*256) {
        int d = i / 32000, r = i % 32000, b = r / 500, q = r % 500;
        long base = (long)b*1500 + q;
        float g0 = b_ih0[d*1500 + q], g1 = b_ih0[d*1500 + 500 + q], g2 = b_ih0[d*1500 + 1000 + q];
        for (int s = 0; s < 9; s++) {
            const float* P = PgiL0 + (long)(d*9 + s)*96000 + base;
            g0 += P[0]; g1 += P[500]; g2 += P[1000];
        }
        float h0v = b_hh0[d*1500 + q], h1v = b_hh0[d*1500 + 500 + q], h2v = b_hh0[d*1500 + 1000 + q];
        for (int s = 0; s < 4; s++) {
            const float* P = PghL0 + (long)(d*4 + s)*96000 + base;
            h0v += P[0]; h1v += P[500]; h2v += P[1000];
        }
        float hp = h0[((long)d*64 + b)*500 + q];
        float rr = sigmoidf_(g0 + h0v);
        float zz = sigmoidf_(g1 + h1v);
        float nn = tanhf(g2 + rr*h2v);
        float o = (1.f - zz)*nn + zz*hp;
        long oo = (long)b*1024 + d*500 + q;
        short h = f2bf(o);
        x1hi[oo] = h; x1lo[oo] = f2bf(o - bf2f(h));
    }
    gbar(bar);

    // ---------------- P3: L1 ih GEMM (S=8x4) ----------------------------------------
    for (int it = blockIdx.x; it < 384; it += NB) {
        int z = it / 192, rem = it % 192, s = rem / 24, nblk = rem % 24;
        mm_core4<1>(x1hi, x1lo, w_ih1 + (long)z*1500*1000,
                    PgiL1 + (long)(z*8 + s)*96000, 1000, 1024, 1500,
                    s*4, min(32, s*4+4), nblk);
    }
    gbar(bar);

    // ---------------- P4: gates L1 -> ht --------------------------------------------
    for (int i = gtid; i < 64000; i += NB*256) {
        int d = i / 32000, r = i % 32000, b = r / 500, q = r % 500;
        long base = (long)b*1500 + q;
        float g0 = b_ih1[d*1500 + q], g1 = b_ih1[d*1500 + 500 + q], g2 = b_ih1[d*1500 + 1000 + q];
        for (int s = 0; s < 8; s++) {
            const float* P = PgiL1 + (long)(d*8 + s)*96000 + base;
            g0 += P[0]; g1 += P[500]; g2 += P[1000];
        }
        float h0v = b_hh1[d*1500 + q], h1v = b_hh1[d*1500 + 500 + q], h2v = b_hh1[d*1500 + 1000 + q];
        for (int s = 0; s < 4; s++) {
            const float* P = PghL1 + (long)(d*4 + s)*96000 + base;
            h0v += P[0]; h1v += P[500]; h2v += P[1000];
        }
        float hp = h0[((long)(2 + d)*64 + b)*500 + q];
        float rr = sigmoidf_(g0 + h0v);
        float zz = sigmoidf_(g1 + h1v);
        float nn = tanhf(g2 + rr*h2v);
        float o = (1.f - zz)*nn + zz*hp;
        long oo = (long)b*1024 + d*500 + q;
        short h = f2bf(o);
        hthi[oo] = h; htlo[oo] = f2bf(o - bf2f(h));
        ht[(long)b*1000 + d*500 + q] = o;
    }
    gbar(bar);

    // ---------------- P5: Wp GEMM (S=32x1) ------------------------------------------
    for (int it = blockIdx.x; it < 512; it += NB) {
        int s = it / 16, nblk = it % 16;
        mm_core4<0>(hthi, htlo, Wp_w, Pwp + (long)s*64000, 1000, 1024, 1000,
                    s, s+1, nblk);
    }
    gbar(bar);

    // ---------------- P6: attention + fused pt (enc via L2, no big LDS) -------------
    for (int b = blockIdx.x; b < 64; b += NB) {
        float ps = 0.f;
        for (int j = tid; j < 1000; j += 256) {
            float v = Wp_b[j];
#pragma unroll
            for (int s = 0; s < 32; s++) v += Pwp[(long)s*64000 + (long)b*1000 + j];
            ps += tanhf(v) * Vp_w[j];
        }
        for (int off = 32; off; off >>= 1) ps += __shfl_down(ps, off);
        if (lane == 0) sm_red[wave] = ps;
        for (int h = tid; h < 1000; h += 256) sm_hts[h] = ht[b*1000 + h];
        __syncthreads();
        if (tid == 0) {
            float tot = sm_red[0] + sm_red[1] + sm_red[2] + sm_red[3];
            float s = 1.f/(1.f + expf(-(tot + Vp_b[0])));
            int len = lengths[b];
            int pt = (int)((float)len * s);
            sm_p[0] = min(len - 5, max(0, pt - 5));
            sm_p[1] = min(len, pt + 6);
        }
        __syncthreads();
        int p0 = sm_p[0], p1 = sm_p[1];
        for (int k = wave; k < 11; k += 4) {
            int row = min(p0 + k, 1023);
            const float* er = enc + ((long)b*1024 + row)*1000;
            float d = 0.f;
            for (int h = lane; h < 1000; h += 64) d += sm_hts[h]*er[h];
            for (int off = 32; off; off >>= 1) d += __shfl_down(d, off);
            if (lane == 0) sm_aa[k] = d;
        }
        __syncthreads();
        if (tid == 0) {
            int nv = min(p1 - p0, 11);
            float m = -1e30f;
            for (int k = 0; k < nv; k++) m = fmaxf(m, sm_aa[k]);
            float ssum = 0.f;
            for (int k = 0; k < 11; k++) { float e = (k < nv) ? expf(sm_aa[k]-m) : 0.f; sm_aa[k] = e; ssum += e; }
            float inv = 1.f/ssum;
            for (int k = 0; k < 11; k++) sm_aa[k] *= inv;
        }
        __syncthreads();
        for (int h = tid; h < 1000; h += 256) {
            float c = 0.f;
#pragma unroll
            for (int k = 0; k < 11; k++) {
                int row = min(p0 + k, 1023);
                c += sm_aa[k]*enc[((long)b*1024 + row)*1000 + h];
            }
            catbf[(long)b*2048 + h]        = f2bf(c);
            catbf[(long)b*2048 + 1000 + h] = f2bf(sm_hts[h]);
        }
        __syncthreads();
    }
    gbar(bar);

    // ---------------- P7: Wc GEMM (S=32x2) ------------------------------------------
    for (int it = blockIdx.x; it < 512; it += NB) {
        int s = it / 16, nblk = it % 16;
        mm_core<0,0>(catbf, Wc_w, nullptr, Pwc + (long)s*64000, 2000, 2048, 1000,
                     s*2, s*2+2, nblk);
    }
    gbar(bar);

    // ---------------- P8: hattn combine + tanh -> habf -------------------------------
    for (int i = gtid; i < 64000; i += NB*256) {
        int b = i / 1000, nn = i % 1000;
        float v = Wc_b[nn];
        for (int s = 0; s < 32; s++) v += Pwc[(long)s*64000 + i];
        habf[(long)b*1024 + nn] = f2bf(tanhf(v));
    }
    gbar(bar);

    // ---------------- P9: output projection + partS epilogue ------------------------
    for (int nblk = blockIdx.x; nblk < 786; nblk += NB) {
        const int N = 50257, K = 1000, Kp = 1024;
        const int l16 = lane & 15, lg = lane >> 4;
        const int n   = nblk*64 + wave*16 + l16;
        const bool ok = n < N;
        const int nc  = ok ? n : (N-1);

        f32x4 acc[4];
#pragma unroll
        for (int mt = 0; mt < 4; mt++) acc[mt] = f32x4{0.f,0.f,0.f,0.f};

        for (int ks = 0; ks < 32; ks++) {
            const int kl = ks*32 + lg*8;
            const short* ap = habf + (long)l16*Kp + kl;
            bf16x8 a0 = *(const bf16x8*)(ap);
            bf16x8 a1 = *(const bf16x8*)(ap + (long)16*Kp);
            bf16x8 a2 = *(const bf16x8*)(ap + (long)32*Kp);
            bf16x8 a3 = *(const bf16x8*)(ap + (long)48*Kp);
            float wv[8];
            const float* wk = out_w + (long)kl*(long)N + nc;
            if (kl + 8 <= K) {
#pragma unroll
                for (int j=0;j<8;j++) wv[j] = wk[(long)j*N];
            } else {
#pragma unroll
                for (int j=0;j<8;j++) wv[j] = (kl+j < K) ? wk[(long)j*N] : 0.f;
            }
            bf16x8 b;
#pragma unroll
            for (int j=0;j<8;j++) b[j] = f2bf(wv[j]);
            acc[0] = __builtin_amdgcn_mfma_f32_16x16x32_bf16(a0, b, acc[0], 0, 0, 0);
            acc[1] = __builtin_amdgcn_mfma_f32_16x16x32_bf16(a1, b, acc[1], 0, 0, 0);
            acc[2] = __builtin_amdgcn_mfma_f32_16x16x32_bf16(a2, b, acc[2], 0, 0, 0);
            acc[3] = __builtin_amdgcn_mfma_f32_16x16x32_bf16(a3, b, acc[3], 0, 0, 0);
        }

        const float bv = ok ? out_b[n] : 0.f;
#pragma unroll
        for (int mt = 0; mt < 4; mt++) {
#pragma unroll
            for (int q = 0; q < 4; q++) {
                int row = mt*16 + lg*4 + q;
                float v = acc[mt][q] + bv;
                if (ok) y[(long)row*N + n] = v;
                float e = ok ? expf(v) : 0.f;
                e += __shfl_xor(e, 1);
                e += __shfl_xor(e, 2);
                e += __shfl_xor(e, 4);
                e += __shfl_xor(e, 8);
                if (l16 == 0) sm_ps[wave*64 + row] = e;
            }
        }
        __syncthreads();
        if (tid < 64)
            partS[(long)tid*786 + nblk] = sm_ps[tid] + sm_ps[64+tid] + sm_ps[128+tid] + sm_ps[192+tid];
        __syncthreads();
    }
    gbar(bar);

    // ---------------- P10: merge partS -> lse ---------------------------------------
    for (int row = blockIdx.x; row < 64; row += NB) {
        float s = 0.f;
        for (int p = tid; p < 786; p += 256) s += partS[(long)row*786 + p];
        for (int off = 32; off; off >>= 1) s += __shfl_down(s, off);
        if (lane == 0) sm_red[wave] = s;
        __syncthreads();
        if (tid == 0) lse[row] = logf(sm_red[0] + sm_red[1] + sm_red[2] + sm_red[3]);
        __syncthreads();
    }
    gbar(bar);

    // ---------------- P11: subtract lse in place ------------------------------------
    for (int i = gtid; i < 64*50257; i += NB*256) {
        int b = i / 50257;
        y[i] -= lse[b];
    }
}

// =====================================================================================
extern "C" void kernel_launch(void* const* d_in, const int* in_sizes, int n_in,
                              void* d_out, int out_size, void* d_ws, size_t ws_size,
                              hipStream_t stream)
{
    const int*   dec_in  = (const int*)  d_in[0];
    const float* attn_h  = (const float*)d_in[1];
    const float* enc     = (const float*)d_in[2];
    // d_in[3] = mask0 (unused: m_w == valid within the window)
    const int*   lengths = (const int*)  d_in[4];
    const float* h0      = (const float*)d_in[5];
    const float* embed   = (const float*)d_in[6];
    const float* w_ih0   = (const float*)d_in[7];
    const float* w_hh0   = (const float*)d_in[8];
    const float* b_ih0   = (const float*)d_in[9];
    const float* b_hh0   = (const float*)d_in[10];
    const float* w_ih1   = (const float*)d_in[11];
    const float* w_hh1   = (const float*)d_in[12];
    const float* b_ih1   = (const float*)d_in[13];
    const float* b_hh1   = (const float*)d_in[14];
    const float* Wp_w    = (const float*)d_in[15];
    const float* Wp_b    = (const float*)d_in[16];
    const float* Vp_w    = (const float*)d_in[17];
    const float* Vp_b    = (const float*)d_in[18];
    const float* Wc_w    = (const float*)d_in[19];
    const float* Wc_b    = (const float*)d_in[20];
    const float* out_w   = (const float*)d_in[21];
    const float* out_b   = (const float*)d_in[22];
    float* y = (float*)d_out;

    // ---- workspace layout (floats), verified non-overlapping ----
    float* ws = (float*)d_ws;
    short* xhi   = (short*)(ws + 0);         // 41,984 fl -> 42,000
    short* xlo   = (short*)(ws + 42000);
    short* h0hi  = (short*)(ws + 84000);     // 65,536 fl -> 65,600
    short* h0lo  = (short*)(ws + 149600);
    short* x1hi  = (short*)(ws + 215200);    // 32,768 fl -> 32,800
    short* x1lo  = (short*)(ws + 248000);
    short* hthi  = (short*)(ws + 280800);
    short* htlo  = (short*)(ws + 313600);
    short* catbf = (short*)(ws + 346400);    // 65,536 fl -> 65,600
    short* habf  = (short*)(ws + 412000);    // 32,768 fl -> 32,800
    float* ht    = ws + 444800;              // 64,000
    float* PgiL0 = ws + 508800;              // 2*9*96000 = 1,728,000
    float* PghL0 = ws + 2236800;             // 2*4*96000 = 768,000
    float* PgiL1 = ws + 3004800;             // 2*8*96000 = 1,536,000
    float* PghL1 = ws + 4540800;             // 768,000
    float* Pwp   = ws + 5308800;             // 32*64000 = 2,048,000
    float* Pwc   = ws + 7356800;             // 2,048,000
    float* partS = ws + 9404800;             // 50,304 -> 50,400
    float* lse   = ws + 9455200;             // 64
    int*   bar   = (int*)(ws + 9455264);     // 528 ints (16 grp cnt, root, 16 gens; padded)

    hipMemsetAsync(bar, 0, 528*sizeof(int), stream);

    k_mega<<<dim3(NB), dim3(256), 0, stream>>>(
        dec_in, attn_h, enc, lengths, h0, embed,
        w_ih0, w_hh0, b_ih0, b_hh0, w_ih1, w_hh1, b_ih1, b_hh1,
        Wp_w, Wp_b, Vp_w, Vp_b, Wc_w, Wc_b, out_w, out_b, y,
        xhi, xlo, h0hi, h0lo, x1hi, x1lo, hthi, htlo,
        catbf, habf, ht, PgiL0, PghL0, PgiL1, PghL1,
        Pwp, Pwc, partS, lse, bar);
}

// Round 10
// 244.227 us; speedup vs baseline: 2.8728x; 2.6691x over previous
//
#include <hip/hip_runtime.h>
#include <hip/hip_bf16.h>
#include <math.h>

typedef __attribute__((ext_vector_type(8))) short bf16x8;
typedef __attribute__((ext_vector_type(4))) float f32x4;

__device__ __forceinline__ float sigmoidf_(float x){ return 1.f/(1.f + expf(-x)); }
__device__ __forceinline__ short f2bf(float x){
    union { __hip_bfloat16 h; short s; } u; u.h = __float2bfloat16(x); return u.s;
}
__device__ __forceinline__ float bf2f(short s){
    union { unsigned u; float f; } v; v.u = ((unsigned)(unsigned short)s) << 16; return v.f;
}

// =====================================================================================
// bf16 MFMA GEMM core (R5 structure: direct loads, compiler-scheduled).
// TRANS=1: W is [N][K] row-major; TRANS=0: W is [K][N] row-major.
// =====================================================================================
template<int TRANS, int BIAS>
__device__ __forceinline__ void mm_core(
    const short* __restrict__ Abf, const float* __restrict__ W,
    const float* __restrict__ bias, float* __restrict__ outP,
    int K, int Kp, int N, int ks0, int ks1, int nblk)
{
    const int lane = threadIdx.x & 63;
    const int wave = threadIdx.x >> 6;
    const int l16  = lane & 15;
    const int lg   = lane >> 4;
    const int n    = nblk*64 + wave*16 + l16;
    const int nc   = min(n, N-1);

    f32x4 acc[4];
#pragma unroll
    for (int mt = 0; mt < 4; mt++) acc[mt] = f32x4{0.f,0.f,0.f,0.f};

    for (int ks = ks0; ks < ks1; ks++) {
        const int kl = ks*32 + lg*8;
        const short* ap = Abf + (long)l16*Kp + kl;
        bf16x8 a0 = *(const bf16x8*)(ap);
        bf16x8 a1 = *(const bf16x8*)(ap + (long)16*Kp);
        bf16x8 a2 = *(const bf16x8*)(ap + (long)32*Kp);
        bf16x8 a3 = *(const bf16x8*)(ap + (long)48*Kp);
        float wv[8];
        if (TRANS) {
            const float* wr = W + (long)nc*K;
            if (kl + 8 <= K) {
                float4 f0 = *(const float4*)(wr + kl);
                float4 f1 = *(const float4*)(wr + kl + 4);
                wv[0]=f0.x; wv[1]=f0.y; wv[2]=f0.z; wv[3]=f0.w;
                wv[4]=f1.x; wv[5]=f1.y; wv[6]=f1.z; wv[7]=f1.w;
            } else {
#pragma unroll
                for (int j=0;j<8;j++) wv[j] = wr[min(kl+j, K-1)];
            }
        } else {
            const float* wk = W + (long)kl*(long)N + nc;
            if (kl + 8 <= K) {
#pragma unroll
                for (int j=0;j<8;j++) wv[j] = wk[(long)j*N];
            } else {
#pragma unroll
                for (int j=0;j<8;j++) wv[j] = (kl+j < K) ? wk[(long)j*N] : 0.f;
            }
        }
        bf16x8 b;
#pragma unroll
        for (int j=0;j<8;j++) b[j] = f2bf(wv[j]);

        acc[0] = __builtin_amdgcn_mfma_f32_16x16x32_bf16(a0, b, acc[0], 0, 0, 0);
        acc[1] = __builtin_amdgcn_mfma_f32_16x16x32_bf16(a1, b, acc[1], 0, 0, 0);
        acc[2] = __builtin_amdgcn_mfma_f32_16x16x32_bf16(a2, b, acc[2], 0, 0, 0);
        acc[3] = __builtin_amdgcn_mfma_f32_16x16x32_bf16(a3, b, acc[3], 0, 0, 0);
    }

    if (n < N) {
        const float bv = BIAS ? bias[n] : 0.f;
#pragma unroll
        for (int mt = 0; mt < 4; mt++) {
#pragma unroll
            for (int q = 0; q < 4; q++) {
                int row = mt*16 + lg*4 + q;
                outP[(long)row*N + n] = acc[mt][q] + bv;
            }
        }
    }
}

// =====================================================================================
// Split-precision (hi+lo bf16, 4 products) core — fp32-class accuracy (pt path).
// =====================================================================================
template<int TRANS>
__device__ __forceinline__ void mm_core4(
    const short* __restrict__ Ahi, const short* __restrict__ Alo,
    const float* __restrict__ W, float* __restrict__ outP,
    int K, int Kp, int N, int ks0, int ks1, int nblk)
{
    const int lane = threadIdx.x & 63;
    const int wave = threadIdx.x >> 6;
    const int l16  = lane & 15;
    const int lg   = lane >> 4;
    const int n    = nblk*64 + wave*16 + l16;
    const int nc   = min(n, N-1);

    f32x4 acc[4];
#pragma unroll
    for (int mt = 0; mt < 4; mt++) acc[mt] = f32x4{0.f,0.f,0.f,0.f};

    for (int ks = ks0; ks < ks1; ks++) {
        const int kl = ks*32 + lg*8;
        const long o0 = (long)l16*Kp + kl;
        bf16x8 ah0 = *(const bf16x8*)(Ahi + o0);
        bf16x8 ah1 = *(const bf16x8*)(Ahi + o0 + (long)16*Kp);
        bf16x8 ah2 = *(const bf16x8*)(Ahi + o0 + (long)32*Kp);
        bf16x8 ah3 = *(const bf16x8*)(Ahi + o0 + (long)48*Kp);
        bf16x8 al0 = *(const bf16x8*)(Alo + o0);
        bf16x8 al1 = *(const bf16x8*)(Alo + o0 + (long)16*Kp);
        bf16x8 al2 = *(const bf16x8*)(Alo + o0 + (long)32*Kp);
        bf16x8 al3 = *(const bf16x8*)(Alo + o0 + (long)48*Kp);
        float wv[8];
        if (TRANS) {
            const float* wr = W + (long)nc*K;
            if (kl + 8 <= K) {
                float4 f0 = *(const float4*)(wr + kl);
                float4 f1 = *(const float4*)(wr + kl + 4);
                wv[0]=f0.x; wv[1]=f0.y; wv[2]=f0.z; wv[3]=f0.w;
                wv[4]=f1.x; wv[5]=f1.y; wv[6]=f1.z; wv[7]=f1.w;
            } else {
#pragma unroll
                for (int j=0;j<8;j++) wv[j] = wr[min(kl+j, K-1)];
            }
        } else {
            const float* wk = W + (long)kl*(long)N + nc;
            if (kl + 8 <= K) {
#pragma unroll
                for (int j=0;j<8;j++) wv[j] = wk[(long)j*N];
            } else {
#pragma unroll
                for (int j=0;j<8;j++) wv[j] = (kl+j < K) ? wk[(long)j*N] : 0.f;
            }
        }
        bf16x8 bh, bl;
#pragma unroll
        for (int j=0;j<8;j++) {
            short h = f2bf(wv[j]);
            bh[j] = h;
            bl[j] = f2bf(wv[j] - bf2f(h));
        }
        acc[0] = __builtin_amdgcn_mfma_f32_16x16x32_bf16(ah0, bh, acc[0], 0, 0, 0);
        acc[1] = __builtin_amdgcn_mfma_f32_16x16x32_bf16(ah1, bh, acc[1], 0, 0, 0);
        acc[2] = __builtin_amdgcn_mfma_f32_16x16x32_bf16(ah2, bh, acc[2], 0, 0, 0);
        acc[3] = __builtin_amdgcn_mfma_f32_16x16x32_bf16(ah3, bh, acc[3], 0, 0, 0);
        acc[0] = __builtin_amdgcn_mfma_f32_16x16x32_bf16(ah0, bl, acc[0], 0, 0, 0);
        acc[1] = __builtin_amdgcn_mfma_f32_16x16x32_bf16(ah1, bl, acc[1], 0, 0, 0);
        acc[2] = __builtin_amdgcn_mfma_f32_16x16x32_bf16(ah2, bl, acc[2], 0, 0, 0);
        acc[3] = __builtin_amdgcn_mfma_f32_16x16x32_bf16(ah3, bl, acc[3], 0, 0, 0);
        acc[0] = __builtin_amdgcn_mfma_f32_16x16x32_bf16(al0, bh, acc[0], 0, 0, 0);
        acc[1] = __builtin_amdgcn_mfma_f32_16x16x32_bf16(al1, bh, acc[1], 0, 0, 0);
        acc[2] = __builtin_amdgcn_mfma_f32_16x16x32_bf16(al2, bh, acc[2], 0, 0, 0);
        acc[3] = __builtin_amdgcn_mfma_f32_16x16x32_bf16(al3, bh, acc[3], 0, 0, 0);
        acc[0] = __builtin_amdgcn_mfma_f32_16x16x32_bf16(al0, bl, acc[0], 0, 0, 0);
        acc[1] = __builtin_amdgcn_mfma_f32_16x16x32_bf16(al1, bl, acc[1], 0, 0, 0);
        acc[2] = __builtin_amdgcn_mfma_f32_16x16x32_bf16(al2, bl, acc[2], 0, 0, 0);
        acc[3] = __builtin_amdgcn_mfma_f32_16x16x32_bf16(al3, bl, acc[3], 0, 0, 0);
    }

    if (n < N) {
#pragma unroll
        for (int mt = 0; mt < 4; mt++) {
#pragma unroll
            for (int q = 0; q < 4; q++) {
                int row = mt*16 + lg*4 + q;
                outP[(long)row*N + n] = acc[mt][q];
            }
        }
    }
}

// ============ prep: hi/lo A matrices, zero tails =====================================
__global__ void k_prep(const int* __restrict__ dec_in, const float* __restrict__ attn_h,
                       const float* __restrict__ embed, const float* __restrict__ h0,
                       short* __restrict__ xhi, short* __restrict__ xlo,
                       short* __restrict__ h0hi, short* __restrict__ h0lo,
                       short* __restrict__ x1hi, short* __restrict__ x1lo,
                       short* __restrict__ hthi, short* __restrict__ htlo,
                       short* __restrict__ habf, short* __restrict__ catbf)
{
    int i = blockIdx.x*256 + threadIdx.x;
    if (i < 64*1312) {                       // x [64][1312]
        int b = i / 1312, k = i % 1312;
        float v = 0.f;
        if (k < 300)       v = embed[(long)dec_in[b]*300 + k];
        else if (k < 1300) v = attn_h[b*1000 + (k-300)];
        short h = f2bf(v);
        xhi[i] = h; xlo[i] = f2bf(v - bf2f(h));
        return;
    }
    i -= 64*1312;
    if (i < 4*64*512) {                      // h0 [4][64][512]
        int d = i >> 15, r = i & 32767, b = r >> 9, k = r & 511;
        float v = (k < 500) ? h0[((long)d*64 + b)*500 + k] : 0.f;
        short h = f2bf(v);
        h0hi[i] = h; h0lo[i] = f2bf(v - bf2f(h));
        return;
    }
    i -= 4*64*512;
    if (i < 1536) {                          // x1/ht hi+lo tails
        int b = i/24; long o = (long)b*1024 + 1000 + i%24;
        x1hi[o]=0; x1lo[o]=0; hthi[o]=0; htlo[o]=0; return;
    }
    i -= 1536;
    if (i < 1536) { int b = i/24; habf[(long)b*1024 + 1000 + i%24] = 0; return; }
    i -= 1536;
    if (i < 3072) { int b = i/48; catbf[(long)b*2048 + 2000 + i%48] = 0; return; }
}

// ============ fused GRU GEMM (split-precision): z<2 ih dir z ; z>=2 hh dir z-2 ========
template<int LAYER>
__global__ __launch_bounds__(256) void k_gru_mm(
    const short* __restrict__ Aih_hi, const short* __restrict__ Aih_lo,
    const short* __restrict__ h0hi,   const short* __restrict__ h0lo,
    const float* __restrict__ w_ih, const float* __restrict__ w_hh,
    float* __restrict__ Pgi, float* __restrict__ Pgh,
    int Kih, int Kpih, int Sih, int stepsih, int Shh, int stepshh)
{
    int z = blockIdx.z, s = blockIdx.y, nblk = blockIdx.x;
    if (z < 2) {
        if (s >= Sih) return;
        int nsteps = Kpih >> 5;
        int ks0 = s*stepsih, ks1 = min(nsteps, ks0 + stepsih);
        if (ks0 >= ks1) return;
        const float* W = w_ih + (long)z*1500*Kih;
        float* outP = Pgi + (long)(z*Sih + s)*96000;
        mm_core4<1>(Aih_hi, Aih_lo, W, outP, Kih, Kpih, 1500, ks0, ks1, nblk);
    } else {
        int d = z - 2;
        if (s >= Shh) return;
        int ks0 = s*stepshh, ks1 = min(16, ks0 + stepshh);
        if (ks0 >= ks1) return;
        const float* W = w_hh + (long)d*1500*500;
        float* outP = Pgh + (long)(d*Shh + s)*96000;
        const long ao = (long)(LAYER*2 + d)*64*512;
        mm_core4<1>(h0hi + ao, h0lo + ao, W, outP, 500, 512, 1500, ks0, ks1, nblk);
    }
}

// ============ NN split-K GEMM, split-precision (Wp) ==================================
__global__ __launch_bounds__(256) void k_nn_split4(
    const short* __restrict__ Ahi, const short* __restrict__ Alo,
    const float* __restrict__ W,
    float* __restrict__ P, int K, int Kp, int N, int steps)
{
    int s = blockIdx.y;
    int ks0 = s*steps, ks1 = min(Kp >> 5, ks0 + steps);
    if (ks0 >= ks1) return;
    mm_core4<0>(Ahi, Alo, W, P + (long)s*64*N, K, Kp, N, ks0, ks1, blockIdx.x);
}

// ============ NN split-K GEMM, single precision (Wc) =================================
__global__ __launch_bounds__(256) void k_nn_split(
    const short* __restrict__ Abf, const float* __restrict__ W,
    float* __restrict__ P, int K, int Kp, int N, int steps)
{
    int s = blockIdx.y;
    int ks0 = s*steps, ks1 = min(Kp >> 5, ks0 + steps);
    if (ks0 >= ks1) return;
    mm_core<0,0>(Abf, W, nullptr, P + (long)s*64*N, K, Kp, N, ks0, ks1, blockIdx.x);
}

// ============ output projection, split-K x2 -> partials ==============================
__global__ __launch_bounds__(256) void k_out_sk(
    const short* __restrict__ Abf, const float* __restrict__ W,
    float* __restrict__ P)
{
    int s = blockIdx.y;
    mm_core<0,0>(Abf, W, nullptr, P + (long)s*64*50257, 1000, 1024, 50257,
                 s*16, s*16+16, blockIdx.x);
}

// ============ combine partials + bias -> y, with fused exp-sum partials ==============
__global__ void k_comb(const float* __restrict__ P, const float* __restrict__ bias,
                       float* __restrict__ y, float* __restrict__ partC)
{
    const int V = 50257;
    int b = blockIdx.y;
    int j = blockIdx.x*256 + threadIdx.x;
    float e = 0.f;
    if (j < V) {
        float v = P[(long)b*V + j] + P[(long)(64 + b)*V + j] + bias[j];
        y[(long)b*V + j] = v;
        e = expf(v);
    }
    for (int off = 32; off; off >>= 1) e += __shfl_down(e, off);
    __shared__ float red[4];
    int lane = threadIdx.x & 63, wave = threadIdx.x >> 6;
    if (lane == 0) red[wave] = e;
    __syncthreads();
    if (threadIdx.x == 0) partC[(long)b*197 + blockIdx.x] = red[0]+red[1]+red[2]+red[3];
}

// ============ merge exp-sum partials -> lse ==========================================
__global__ void k_merge2(const float* __restrict__ partC, float* __restrict__ lse)
{
    int t = threadIdx.x;
    int row = t & 63, seg = t >> 6;
    float s = 0.f;
    for (int p = seg; p < 197; p += 4) s += partC[(long)row*197 + p];
    __shared__ float red[256];
    red[t] = s;
    __syncthreads();
    if (t < 64) lse[row] = logf(red[row] + red[row+64] + red[row+128] + red[row+192]);
}

// ============ GRU gates: sum split-K partials + biases ===============================
template<int LAYER>
__global__ void k_gates(const float* __restrict__ Pgi, const float* __restrict__ Pgh,
                        const float* __restrict__ h0,
                        const float* __restrict__ b_ih, const float* __restrict__ b_hh,
                        short* __restrict__ outhi, short* __restrict__ outlo,
                        float* __restrict__ ht, int SI, int SH)
{
    const int d = blockIdx.y;
    int i = blockIdx.x*256 + threadIdx.x;
    if (i >= 32000) return;
    int b = i / 500, q = i % 500;
    long base = (long)b*1500 + q;
    float g0 = b_ih[d*1500 + q], g1 = b_ih[d*1500 + 500 + q], g2 = b_ih[d*1500 + 1000 + q];
    for (int s = 0; s < SI; s++) {
        const float* P = Pgi + (long)(d*SI + s)*96000 + base;
        g0 += P[0]; g1 += P[500]; g2 += P[1000];
    }
    float h0v = b_hh[d*1500 + q], h1v = b_hh[d*1500 + 500 + q], h2v = b_hh[d*1500 + 1000 + q];
    for (int s = 0; s < SH; s++) {
        const float* P = Pgh + (long)(d*SH + s)*96000 + base;
        h0v += P[0]; h1v += P[500]; h2v += P[1000];
    }
    float hp = h0[((long)(LAYER*2 + d)*64 + b)*500 + q];
    float r = sigmoidf_(g0 + h0v);
    float z = sigmoidf_(g1 + h1v);
    float nn = tanhf(g2 + r*h2v);
    float o = (1.f - z)*nn + z*hp;
    long oo = (long)b*1024 + d*500 + q;
    short h = f2bf(o);
    outhi[oo] = h; outlo[oo] = f2bf(o - bf2f(h));
    if (LAYER == 1) ht[(long)b*1000 + d*500 + q] = o;
}

// ============ pt / window bounds (sums Wp partials) ===================================
__global__ void k_pt(const float* __restrict__ Pwp, const float* __restrict__ Wp_b,
                     const float* __restrict__ Vp_w, const float* __restrict__ Vp_b,
                     const int* __restrict__ lengths, int* __restrict__ p01, int S)
{
    int b = blockIdx.x;
    float ps = 0.f;
    for (int j = threadIdx.x; j < 1000; j += 256) {
        float v = Wp_b[j];
        for (int s = 0; s < S; s++) v += Pwp[(long)s*64000 + (long)b*1000 + j];
        ps += tanhf(v) * Vp_w[j];
    }
    for (int off = 32; off; off >>= 1) ps += __shfl_down(ps, off);
    __shared__ float red[4];
    int lane = threadIdx.x & 63, wave = threadIdx.x >> 6;
    if (lane == 0) red[wave] = ps;
    __syncthreads();
    if (threadIdx.x == 0) {
        float tot = red[0] + red[1] + red[2] + red[3];
        float s = 1.f/(1.f + expf(-(tot + Vp_b[0])));
        int len = lengths[b];
        int pt = (int)((float)len * s);
        int P0 = min(len - 5, max(0, pt - 5));
        int P1 = min(len, pt + 6);
        p01[2*b] = P0; p01[2*b+1] = P1;
    }
}

// ============ windowed attention; writes catbf [64][2048] bf16 ========================
__global__ void k_attn(const float* __restrict__ enc, const float* __restrict__ ht,
                       const int* __restrict__ p01, short* __restrict__ catbf)
{
    int b = blockIdx.x;
    __shared__ float hts[1000];
    __shared__ float hs[11][1000];
    __shared__ float aa[16];
    int p0 = p01[2*b], p1 = p01[2*b+1];
    for (int h = threadIdx.x; h < 1000; h += 256) hts[h] = ht[b*1000 + h];
    for (int k = 0; k < 11; k++) {
        int row = min(p0 + k, 1023);
        const float* er = enc + ((long)b*1024 + row)*1000;
        for (int h = threadIdx.x; h < 1000; h += 256) hs[k][h] = er[h];
    }
    __syncthreads();
    int lane = threadIdx.x & 63, wave = threadIdx.x >> 6;
    for (int k = wave; k < 11; k += 4) {
        float ps = 0.f;
        for (int h = lane; h < 1000; h += 64) ps += hts[h]*hs[k][h];
        for (int off = 32; off; off >>= 1) ps += __shfl_down(ps, off);
        if (lane == 0) aa[k] = ps;
    }
    __syncthreads();
    if (threadIdx.x == 0) {
        int nv = min(p1 - p0, 11);
        float m = -1e30f;
        for (int k = 0; k < nv; k++) m = fmaxf(m, aa[k]);
        float ssum = 0.f;
        for (int k = 0; k < 11; k++) { float e = (k < nv) ? expf(aa[k]-m) : 0.f; aa[k] = e; ssum += e; }
        float inv = 1.f/ssum;
        for (int k = 0; k < 11; k++) aa[k] *= inv;
    }
    __syncthreads();
    for (int h = threadIdx.x; h < 1000; h += 256) {
        float c = 0.f;
#pragma unroll
        for (int k = 0; k < 11; k++) c += aa[k]*hs[k][h];
        catbf[(long)b*2048 + h]        = f2bf(c);
        catbf[(long)b*2048 + 1000 + h] = f2bf(hts[h]);
    }
}

// ============ combine Wc partials + tanh -> habf bf16 =================================
__global__ void k_hattn(const float* __restrict__ Pwc, const float* __restrict__ Wc_b,
                        short* __restrict__ habf, int S)
{
    int i = blockIdx.x*256 + threadIdx.x;
    if (i >= 64000) return;
    int b = i / 1000, nn = i % 1000;
    float v = Wc_b[nn];
    for (int s = 0; s < S; s++) v += Pwc[(long)s*64000 + i];
    habf[(long)b*1024 + nn] = f2bf(tanhf(v));
}

// ============ final subtract =========================================================
__global__ void k_sub(float* __restrict__ y, const float* __restrict__ lse)
{
    const int V = 50257;
    int b = blockIdx.y;
    int j = blockIdx.x*256 + threadIdx.x;
    if (j < V) y[(long)b*V + j] -= lse[b];
}

// =====================================================================================
extern "C" void kernel_launch(void* const* d_in, const int* in_sizes, int n_in,
                              void* d_out, int out_size, void* d_ws, size_t ws_size,
                              hipStream_t stream)
{
    const int*   dec_in  = (const int*)  d_in[0];
    const float* attn_h  = (const float*)d_in[1];
    const float* enc     = (const float*)d_in[2];
    // d_in[3] = mask0 (unused: m_w == valid within the window)
    const int*   lengths = (const int*)  d_in[4];
    const float* h0      = (const float*)d_in[5];
    const float* embed   = (const float*)d_in[6];
    const float* w_ih0   = (const float*)d_in[7];
    const float* w_hh0   = (const float*)d_in[8];
    const float* b_ih0   = (const float*)d_in[9];
    const float* b_hh0   = (const float*)d_in[10];
    const float* w_ih1   = (const float*)d_in[11];
    const float* w_hh1   = (const float*)d_in[12];
    const float* b_ih1   = (const float*)d_in[13];
    const float* b_hh1   = (const float*)d_in[14];
    const float* Wp_w    = (const float*)d_in[15];
    const float* Wp_b    = (const float*)d_in[16];
    const float* Vp_w    = (const float*)d_in[17];
    const float* Vp_b    = (const float*)d_in[18];
    const float* Wc_w    = (const float*)d_in[19];
    const float* Wc_b    = (const float*)d_in[20];
    const float* out_w   = (const float*)d_in[21];
    const float* out_b   = (const float*)d_in[22];
    float* y = (float*)d_out;

    // ---- workspace layout, FLOAT units; NO overlaps (verified sizes) ----
    float* ws = (float*)d_ws;
    short* xhi   = (short*)(ws + 0);        // 41,984 fl -> 42,000
    short* xlo   = (short*)(ws + 42000);
    short* h0hi  = (short*)(ws + 84000);    // 65,536 fl -> 65,600
    short* h0lo  = (short*)(ws + 149600);
    short* x1hi  = (short*)(ws + 215200);   // 32,768 fl -> 32,800
    short* x1lo  = (short*)(ws + 248000);
    short* hthi  = (short*)(ws + 280800);
    short* htlo  = (short*)(ws + 313600);
    short* catbf = (short*)(ws + 346400);   // 65,536 fl -> 65,600
    short* habf  = (short*)(ws + 412000);   // 32,768 fl -> 32,800
    float* ht    = ws + 444800;             // 64,000
    float* Pgi   = ws + 508800;             // 960,000
    float* Pgh   = ws + 1468800;            // 384,000
    float* Pwp   = ws + 1852800;            // 512,000
    float* Pwc   = ws + 2364800;            // 512,000
    float* Pout  = ws + 2876800;            // 2*64*50257 = 6,432,896 -> 6,433,000
    float* partC = ws + 9309800;            // 64*197 = 12,608 -> 12,700
    float* lse   = ws + 9322500;            // 64
    int*   p01   = (int*)(ws + 9322600);    // 128
    // total ~9.33M floats = 37.3 MB (R9 used 37.8 MB OK)

    dim3 B256(256);

    k_prep<<<dim3((64*1312 + 4*64*512 + 1536 + 1536 + 3072 + 255)/256), B256, 0, stream>>>(
        dec_in, attn_h, embed, h0, xhi, xlo, h0hi, h0lo, x1hi, x1lo, hthi, htlo, habf, catbf);

    // GRU layer 0: ih K=1300 Kp=1312 (41 steps, S=5x9), hh K=500 Kp=512 (16 steps, S=2x8)
    k_gru_mm<0><<<dim3(24, 5, 4), B256, 0, stream>>>(
        xhi, xlo, h0hi, h0lo, w_ih0, w_hh0, Pgi, Pgh, 1300, 1312, 5, 9, 2, 8);
    k_gates<0><<<dim3(125, 2), B256, 0, stream>>>(Pgi, Pgh, h0, b_ih0, b_hh0, x1hi, x1lo, ht, 5, 2);

    // GRU layer 1: ih K=1000 Kp=1024 (32 steps, S=4x8)
    k_gru_mm<1><<<dim3(24, 4, 4), B256, 0, stream>>>(
        x1hi, x1lo, h0hi, h0lo, w_ih1, w_hh1, Pgi, Pgh, 1000, 1024, 4, 8, 2, 8);
    k_gates<1><<<dim3(125, 2), B256, 0, stream>>>(Pgi, Pgh, h0, b_ih1, b_hh1, hthi, htlo, ht, 4, 2);

    // predictive window: Wp (NN, K=1000 Kp=1024, split-precision)
    k_nn_split4<<<dim3(16, 8), B256, 0, stream>>>(hthi, htlo, Wp_w, Pwp, 1000, 1024, 1000, 4);
    k_pt<<<dim3(64), B256, 0, stream>>>(Pwp, Wp_b, Vp_w, Vp_b, lengths, p01, 8);

    // local attention -> catbf; Wc (NN, K=2000 Kp=2048, single bf16)
    k_attn<<<dim3(64), B256, 0, stream>>>(enc, ht, p01, catbf);
    k_nn_split<<<dim3(16, 8), B256, 0, stream>>>(catbf, Wc_w, Pwc, 2000, 2048, 1000, 8);
    k_hattn<<<dim3(250), B256, 0, stream>>>(Pwc, Wc_b, habf, 8);

    // output projection: split-K x2 -> combine (+bias, exp-sum partials) -> lse -> sub
    k_out_sk<<<dim3(786, 2), B256, 0, stream>>>(habf, out_w, Pout);
    k_comb<<<dim3(197, 64), B256, 0, stream>>>(Pout, out_b, y, partC);
    k_merge2<<<dim3(1), B256, 0, stream>>>(partC, lse);
    k_sub<<<dim3(197, 64), B256, 0, stream>>>(y, lse);
}

// Round 11
// 243.266 us; speedup vs baseline: 2.8842x; 1.0040x over previous
//
#include <hip/hip_runtime.h>
#include <hip/hip_bf16.h>
#include <math.h>

typedef __attribute__((ext_vector_type(8))) short bf16x8;
typedef __attribute__((ext_vector_type(4))) float f32x4;

__device__ __forceinline__ float sigmoidf_(float x){ return 1.f/(1.f + expf(-x)); }
__device__ __forceinline__ short f2bf(float x){
    union { __hip_bfloat16 h; short s; } u; u.h = __float2bfloat16(x); return u.s;
}
__device__ __forceinline__ float bf2f(short s){
    union { unsigned u; float f; } v; v.u = ((unsigned)(unsigned short)s) << 16; return v.f;
}

// =====================================================================================
// bf16 MFMA GEMM core (R5 structure: direct loads, compiler-scheduled).
// TRANS=1: W is [N][K] row-major; TRANS=0: W is [K][N] row-major.
// =====================================================================================
template<int TRANS, int BIAS>
__device__ __forceinline__ void mm_core(
    const short* __restrict__ Abf, const float* __restrict__ W,
    const float* __restrict__ bias, float* __restrict__ outP,
    int K, int Kp, int N, int ks0, int ks1, int nblk)
{
    const int lane = threadIdx.x & 63;
    const int wave = threadIdx.x >> 6;
    const int l16  = lane & 15;
    const int lg   = lane >> 4;
    const int n    = nblk*64 + wave*16 + l16;
    const int nc   = min(n, N-1);

    f32x4 acc[4];
#pragma unroll
    for (int mt = 0; mt < 4; mt++) acc[mt] = f32x4{0.f,0.f,0.f,0.f};

    for (int ks = ks0; ks < ks1; ks++) {
        const int kl = ks*32 + lg*8;
        const short* ap = Abf + (long)l16*Kp + kl;
        bf16x8 a0 = *(const bf16x8*)(ap);
        bf16x8 a1 = *(const bf16x8*)(ap + (long)16*Kp);
        bf16x8 a2 = *(const bf16x8*)(ap + (long)32*Kp);
        bf16x8 a3 = *(const bf16x8*)(ap + (long)48*Kp);
        float wv[8];
        if (TRANS) {
            const float* wr = W + (long)nc*K;
            if (kl + 8 <= K) {
                float4 f0 = *(const float4*)(wr + kl);
                float4 f1 = *(const float4*)(wr + kl + 4);
                wv[0]=f0.x; wv[1]=f0.y; wv[2]=f0.z; wv[3]=f0.w;
                wv[4]=f1.x; wv[5]=f1.y; wv[6]=f1.z; wv[7]=f1.w;
            } else {
#pragma unroll
                for (int j=0;j<8;j++) wv[j] = wr[min(kl+j, K-1)];
            }
        } else {
            const float* wk = W + (long)kl*(long)N + nc;
            if (kl + 8 <= K) {
#pragma unroll
                for (int j=0;j<8;j++) wv[j] = wk[(long)j*N];
            } else {
#pragma unroll
                for (int j=0;j<8;j++) wv[j] = (kl+j < K) ? wk[(long)j*N] : 0.f;
            }
        }
        bf16x8 b;
#pragma unroll
        for (int j=0;j<8;j++) b[j] = f2bf(wv[j]);

        acc[0] = __builtin_amdgcn_mfma_f32_16x16x32_bf16(a0, b, acc[0], 0, 0, 0);
        acc[1] = __builtin_amdgcn_mfma_f32_16x16x32_bf16(a1, b, acc[1], 0, 0, 0);
        acc[2] = __builtin_amdgcn_mfma_f32_16x16x32_bf16(a2, b, acc[2], 0, 0, 0);
        acc[3] = __builtin_amdgcn_mfma_f32_16x16x32_bf16(a3, b, acc[3], 0, 0, 0);
    }

    if (n < N) {
        const float bv = BIAS ? bias[n] : 0.f;
#pragma unroll
        for (int mt = 0; mt < 4; mt++) {
#pragma unroll
            for (int q = 0; q < 4; q++) {
                int row = mt*16 + lg*4 + q;
                outP[(long)row*N + n] = acc[mt][q] + bv;
            }
        }
    }
}

// =====================================================================================
// Split-precision (hi+lo bf16, 4 products) core — fp32-class accuracy (pt path).
// =====================================================================================
template<int TRANS>
__device__ __forceinline__ void mm_core4(
    const short* __restrict__ Ahi, const short* __restrict__ Alo,
    const float* __restrict__ W, float* __restrict__ outP,
    int K, int Kp, int N, int ks0, int ks1, int nblk)
{
    const int lane = threadIdx.x & 63;
    const int wave = threadIdx.x >> 6;
    const int l16  = lane & 15;
    const int lg   = lane >> 4;
    const int n    = nblk*64 + wave*16 + l16;
    const int nc   = min(n, N-1);

    f32x4 acc[4];
#pragma unroll
    for (int mt = 0; mt < 4; mt++) acc[mt] = f32x4{0.f,0.f,0.f,0.f};

    for (int ks = ks0; ks < ks1; ks++) {
        const int kl = ks*32 + lg*8;
        const long o0 = (long)l16*Kp + kl;
        bf16x8 ah0 = *(const bf16x8*)(Ahi + o0);
        bf16x8 ah1 = *(const bf16x8*)(Ahi + o0 + (long)16*Kp);
        bf16x8 ah2 = *(const bf16x8*)(Ahi + o0 + (long)32*Kp);
        bf16x8 ah3 = *(const bf16x8*)(Ahi + o0 + (long)48*Kp);
        bf16x8 al0 = *(const bf16x8*)(Alo + o0);
        bf16x8 al1 = *(const bf16x8*)(Alo + o0 + (long)16*Kp);
        bf16x8 al2 = *(const bf16x8*)(Alo + o0 + (long)32*Kp);
        bf16x8 al3 = *(const bf16x8*)(Alo + o0 + (long)48*Kp);
        float wv[8];
        if (TRANS) {
            const float* wr = W + (long)nc*K;
            if (kl + 8 <= K) {
                float4 f0 = *(const float4*)(wr + kl);
                float4 f1 = *(const float4*)(wr + kl + 4);
                wv[0]=f0.x; wv[1]=f0.y; wv[2]=f0.z; wv[3]=f0.w;
                wv[4]=f1.x; wv[5]=f1.y; wv[6]=f1.z; wv[7]=f1.w;
            } else {
#pragma unroll
                for (int j=0;j<8;j++) wv[j] = wr[min(kl+j, K-1)];
            }
        } else {
            const float* wk = W + (long)kl*(long)N + nc;
            if (kl + 8 <= K) {
#pragma unroll
                for (int j=0;j<8;j++) wv[j] = wk[(long)j*N];
            } else {
#pragma unroll
                for (int j=0;j<8;j++) wv[j] = (kl+j < K) ? wk[(long)j*N] : 0.f;
            }
        }
        bf16x8 bh, bl;
#pragma unroll
        for (int j=0;j<8;j++) {
            short h = f2bf(wv[j]);
            bh[j] = h;
            bl[j] = f2bf(wv[j] - bf2f(h));
        }
        acc[0] = __builtin_amdgcn_mfma_f32_16x16x32_bf16(ah0, bh, acc[0], 0, 0, 0);
        acc[1] = __builtin_amdgcn_mfma_f32_16x16x32_bf16(ah1, bh, acc[1], 0, 0, 0);
        acc[2] = __builtin_amdgcn_mfma_f32_16x16x32_bf16(ah2, bh, acc[2], 0, 0, 0);
        acc[3] = __builtin_amdgcn_mfma_f32_16x16x32_bf16(ah3, bh, acc[3], 0, 0, 0);
        acc[0] = __builtin_amdgcn_mfma_f32_16x16x32_bf16(ah0, bl, acc[0], 0, 0, 0);
        acc[1] = __builtin_amdgcn_mfma_f32_16x16x32_bf16(ah1, bl, acc[1], 0, 0, 0);
        acc[2] = __builtin_amdgcn_mfma_f32_16x16x32_bf16(ah2, bl, acc[2], 0, 0, 0);
        acc[3] = __builtin_amdgcn_mfma_f32_16x16x32_bf16(ah3, bl, acc[3], 0, 0, 0);
        acc[0] = __builtin_amdgcn_mfma_f32_16x16x32_bf16(al0, bh, acc[0], 0, 0, 0);
        acc[1] = __builtin_amdgcn_mfma_f32_16x16x32_bf16(al1, bh, acc[1], 0, 0, 0);
        acc[2] = __builtin_amdgcn_mfma_f32_16x16x32_bf16(al2, bh, acc[2], 0, 0, 0);
        acc[3] = __builtin_amdgcn_mfma_f32_16x16x32_bf16(al3, bh, acc[3], 0, 0, 0);
        acc[0] = __builtin_amdgcn_mfma_f32_16x16x32_bf16(al0, bl, acc[0], 0, 0, 0);
        acc[1] = __builtin_amdgcn_mfma_f32_16x16x32_bf16(al1, bl, acc[1], 0, 0, 0);
        acc[2] = __builtin_amdgcn_mfma_f32_16x16x32_bf16(al2, bl, acc[2], 0, 0, 0);
        acc[3] = __builtin_amdgcn_mfma_f32_16x16x32_bf16(al3, bl, acc[3], 0, 0, 0);
    }

    if (n < N) {
#pragma unroll
        for (int mt = 0; mt < 4; mt++) {
#pragma unroll
            for (int q = 0; q < 4; q++) {
                int row = mt*16 + lg*4 + q;
                outP[(long)row*N + n] = acc[mt][q];
            }
        }
    }
}

// ============ prep: hi/lo A matrices, zero tails =====================================
__global__ void k_prep(const int* __restrict__ dec_in, const float* __restrict__ attn_h,
                       const float* __restrict__ embed, const float* __restrict__ h0,
                       short* __restrict__ xhi, short* __restrict__ xlo,
                       short* __restrict__ h0hi, short* __restrict__ h0lo,
                       short* __restrict__ x1hi, short* __restrict__ x1lo,
                       short* __restrict__ hthi, short* __restrict__ htlo,
                       short* __restrict__ habf, short* __restrict__ catbf)
{
    int i = blockIdx.x*256 + threadIdx.x;
    if (i < 64*1312) {                       // x [64][1312]
        int b = i / 1312, k = i % 1312;
        float v = 0.f;
        if (k < 300)       v = embed[(long)dec_in[b]*300 + k];
        else if (k < 1300) v = attn_h[b*1000 + (k-300)];
        short h = f2bf(v);
        xhi[i] = h; xlo[i] = f2bf(v - bf2f(h));
        return;
    }
    i -= 64*1312;
    if (i < 4*64*512) {                      // h0 [4][64][512]
        int d = i >> 15, r = i & 32767, b = r >> 9, k = r & 511;
        float v = (k < 500) ? h0[((long)d*64 + b)*500 + k] : 0.f;
        short h = f2bf(v);
        h0hi[i] = h; h0lo[i] = f2bf(v - bf2f(h));
        return;
    }
    i -= 4*64*512;
    if (i < 1536) {                          // x1/ht hi+lo tails
        int b = i/24; long o = (long)b*1024 + 1000 + i%24;
        x1hi[o]=0; x1lo[o]=0; hthi[o]=0; htlo[o]=0; return;
    }
    i -= 1536;
    if (i < 1536) { int b = i/24; habf[(long)b*1024 + 1000 + i%24] = 0; return; }
    i -= 1536;
    if (i < 3072) { int b = i/48; catbf[(long)b*2048 + 2000 + i%48] = 0; return; }
}

// ============ GRU GEMMs not needing x1: z 0,1=L0ih; 2,3=L0hh; 4,5=L1hh ===============
__global__ __launch_bounds__(256) void k_gru_mm0(
    const short* __restrict__ xhi, const short* __restrict__ xlo,
    const short* __restrict__ h0hi, const short* __restrict__ h0lo,
    const float* __restrict__ w_ih0, const float* __restrict__ w_hh0,
    const float* __restrict__ w_hh1,
    float* __restrict__ PgiL0, float* __restrict__ PghL0, float* __restrict__ PghL1)
{
    int z = blockIdx.z, s = blockIdx.y, nblk = blockIdx.x;
    if (z < 2) {                              // L0 ih: K=1300 Kp=1312, 41 ksteps, S=5x9
        mm_core4<1>(xhi, xlo, w_ih0 + (long)z*1500*1300,
                    PgiL0 + (long)(z*5 + s)*96000, 1300, 1312, 1500,
                    s*9, min(41, s*9+9), nblk);
    } else {
        if (s >= 2) return;                   // hh: K=500 Kp=512, 16 ksteps, S=2x8
        int d = (z < 4) ? (z - 2) : (z - 4);
        const float* W = ((z < 4) ? w_hh0 : w_hh1) + (long)d*750000;
        float* outP = ((z < 4) ? PghL0 : PghL1) + (long)(d*2 + s)*96000;
        const long ao = (long)(((z < 4) ? 0 : 2) + d)*32768;
        mm_core4<1>(h0hi + ao, h0lo + ao, W, outP, 500, 512, 1500, s*8, s*8+8, nblk);
    }
}

// ============ L1 ih GEMM (needs x1): z 0,1 = dirs; S=4x8 =============================
__global__ __launch_bounds__(256) void k_gru_ih1(
    const short* __restrict__ x1hi, const short* __restrict__ x1lo,
    const float* __restrict__ w_ih1, float* __restrict__ PgiL1)
{
    int z = blockIdx.z, s = blockIdx.y, nblk = blockIdx.x;
    mm_core4<1>(x1hi, x1lo, w_ih1 + (long)z*1500*1000,
                PgiL1 + (long)(z*4 + s)*96000, 1000, 1024, 1500,
                s*8, min(32, s*8+8), nblk);
}

// ============ NN split-K GEMM, split-precision (Wp) ==================================
__global__ __launch_bounds__(256) void k_nn_split4(
    const short* __restrict__ Ahi, const short* __restrict__ Alo,
    const float* __restrict__ W,
    float* __restrict__ P, int K, int Kp, int N, int steps)
{
    int s = blockIdx.y;
    int ks0 = s*steps, ks1 = min(Kp >> 5, ks0 + steps);
    if (ks0 >= ks1) return;
    mm_core4<0>(Ahi, Alo, W, P + (long)s*64*N, K, Kp, N, ks0, ks1, blockIdx.x);
}

// ============ NN split-K GEMM, single precision (Wc) =================================
__global__ __launch_bounds__(256) void k_nn_split(
    const short* __restrict__ Abf, const float* __restrict__ W,
    float* __restrict__ P, int K, int Kp, int N, int steps)
{
    int s = blockIdx.y;
    int ks0 = s*steps, ks1 = min(Kp >> 5, ks0 + steps);
    if (ks0 >= ks1) return;
    mm_core<0,0>(Abf, W, nullptr, P + (long)s*64*N, K, Kp, N, ks0, ks1, blockIdx.x);
}

// ============ output projection (single precision, bias) =============================
__global__ __launch_bounds__(256) void k_out_mm(
    const short* __restrict__ Abf, const float* __restrict__ W,
    const float* __restrict__ bias, float* __restrict__ y)
{
    mm_core<0,1>(Abf, W, bias, y, 1000, 1024, 50257, 0, 32, blockIdx.x);
}

// ============ GRU gates: sum split-K partials + biases ===============================
template<int LAYER>
__global__ void k_gates(const float* __restrict__ Pgi, const float* __restrict__ Pgh,
                        const float* __restrict__ h0,
                        const float* __restrict__ b_ih, const float* __restrict__ b_hh,
                        short* __restrict__ outhi, short* __restrict__ outlo,
                        float* __restrict__ ht, int SI, int SH)
{
    const int d = blockIdx.y;
    int i = blockIdx.x*256 + threadIdx.x;
    if (i >= 32000) return;
    int b = i / 500, q = i % 500;
    long base = (long)b*1500 + q;
    float g0 = b_ih[d*1500 + q], g1 = b_ih[d*1500 + 500 + q], g2 = b_ih[d*1500 + 1000 + q];
    for (int s = 0; s < SI; s++) {
        const float* P = Pgi + (long)(d*SI + s)*96000 + base;
        g0 += P[0]; g1 += P[500]; g2 += P[1000];
    }
    float h0v = b_hh[d*1500 + q], h1v = b_hh[d*1500 + 500 + q], h2v = b_hh[d*1500 + 1000 + q];
    for (int s = 0; s < SH; s++) {
        const float* P = Pgh + (long)(d*SH + s)*96000 + base;
        h0v += P[0]; h1v += P[500]; h2v += P[1000];
    }
    float hp = h0[((long)(LAYER*2 + d)*64 + b)*500 + q];
    float r = sigmoidf_(g0 + h0v);
    float z = sigmoidf_(g1 + h1v);
    float nn = tanhf(g2 + r*h2v);
    float o = (1.f - z)*nn + z*hp;
    long oo = (long)b*1024 + d*500 + q;
    short h = f2bf(o);
    outhi[oo] = h; outlo[oo] = f2bf(o - bf2f(h));
    if (LAYER == 1) ht[(long)b*1000 + d*500 + q] = o;
}

// ============ windowed attention with fused pt; writes catbf [64][2048] bf16 ==========
__global__ void k_attn(const float* __restrict__ enc, const float* __restrict__ ht,
                       const float* __restrict__ Pwp, const float* __restrict__ Wp_b,
                       const float* __restrict__ Vp_w, const float* __restrict__ Vp_b,
                       const int* __restrict__ lengths, short* __restrict__ catbf)
{
    int b = blockIdx.x;
    __shared__ float hts[1000];
    __shared__ float hs[11][1000];
    __shared__ float aa[16];
    __shared__ float red[4];
    __shared__ int sp[2];
    int tid = threadIdx.x;
    int lane = tid & 63, wave = tid >> 6;

    // ---- fused pt: sum Wp partials, tanh, dot with Vp ----
    float ps = 0.f;
    for (int j = tid; j < 1000; j += 256) {
        float v = Wp_b[j];
#pragma unroll
        for (int s = 0; s < 8; s++) v += Pwp[(long)s*64000 + (long)b*1000 + j];
        ps += tanhf(v) * Vp_w[j];
    }
    for (int off = 32; off; off >>= 1) ps += __shfl_down(ps, off);
    if (lane == 0) red[wave] = ps;
    for (int h = tid; h < 1000; h += 256) hts[h] = ht[b*1000 + h];
    __syncthreads();
    if (tid == 0) {
        float tot = red[0] + red[1] + red[2] + red[3];
        float s = 1.f/(1.f + expf(-(tot + Vp_b[0])));
        int len = lengths[b];
        int pt = (int)((float)len * s);
        sp[0] = min(len - 5, max(0, pt - 5));
        sp[1] = min(len, pt + 6);
    }
    __syncthreads();
    int p0 = sp[0], p1 = sp[1];

    for (int k = 0; k < 11; k++) {
        int row = min(p0 + k, 1023);
        const float* er = enc + ((long)b*1024 + row)*1000;
        for (int h = tid; h < 1000; h += 256) hs[k][h] = er[h];
    }
    __syncthreads();
    for (int k = wave; k < 11; k += 4) {
        float d = 0.f;
        for (int h = lane; h < 1000; h += 64) d += hts[h]*hs[k][h];
        for (int off = 32; off; off >>= 1) d += __shfl_down(d, off);
        if (lane == 0) aa[k] = d;
    }
    __syncthreads();
    if (tid == 0) {
        int nv = min(p1 - p0, 11);
        float m = -1e30f;
        for (int k = 0; k < nv; k++) m = fmaxf(m, aa[k]);
        float ssum = 0.f;
        for (int k = 0; k < 11; k++) { float e = (k < nv) ? expf(aa[k]-m) : 0.f; aa[k] = e; ssum += e; }
        float inv = 1.f/ssum;
        for (int k = 0; k < 11; k++) aa[k] *= inv;
    }
    __syncthreads();
    for (int h = tid; h < 1000; h += 256) {
        float c = 0.f;
#pragma unroll
        for (int k = 0; k < 11; k++) c += aa[k]*hs[k][h];
        catbf[(long)b*2048 + h]        = f2bf(c);
        catbf[(long)b*2048 + 1000 + h] = f2bf(hts[h]);
    }
}

// ============ combine Wc partials + tanh -> habf bf16 =================================
__global__ void k_hattn(const float* __restrict__ Pwc, const float* __restrict__ Wc_b,
                        short* __restrict__ habf, int S)
{
    int i = blockIdx.x*256 + threadIdx.x;
    if (i >= 64000) return;
    int b = i / 1000, nn = i % 1000;
    float v = Wc_b[nn];
    for (int s = 0; s < S; s++) v += Pwc[(long)s*64000 + i];
    habf[(long)b*1024 + nn] = f2bf(tanhf(v));
}

// ============ log_softmax partials (online m,s per 1/8 row slice) ====================
__global__ void k_lse_part(const float* __restrict__ y, float* __restrict__ part)
{
    const int V = 50257;
    int b = blockIdx.x >> 3, p = blockIdx.x & 7;
    const int Vc = (V + 7)/8;
    int start = p*Vc, end = min(V, start + Vc);
    float m = -1e30f, s = 0.f;
    for (int j = start + threadIdx.x; j < end; j += 256) {
        float v = y[(long)b*V + j];
        if (v > m) { s = s*expf(m - v) + 1.f; m = v; }
        else       { s += expf(v - m); }
    }
    __shared__ float ms[256], ss[256];
    ms[threadIdx.x] = m; ss[threadIdx.x] = s;
    __syncthreads();
    for (int st = 128; st; st >>= 1) {
        if (threadIdx.x < st) {
            float m1 = ms[threadIdx.x], s1 = ss[threadIdx.x];
            float m2 = ms[threadIdx.x+st], s2 = ss[threadIdx.x+st];
            float M = fmaxf(m1, m2);
            ms[threadIdx.x] = M;
            ss[threadIdx.x] = s1*expf(m1-M) + s2*expf(m2-M);
        }
        __syncthreads();
    }
    if (threadIdx.x == 0) { part[2*blockIdx.x] = ms[0]; part[2*blockIdx.x+1] = ss[0]; }
}

// ============ fused merge + subtract: each block merges its row's 8 partials =========
__global__ void k_sub2(float* __restrict__ y, const float* __restrict__ part)
{
    const int V = 50257;
    int b = blockIdx.y;
    float M = -1e30f, S = 0.f;
#pragma unroll
    for (int p = 0; p < 8; p++) {
        float m2 = part[2*(b*8+p)], s2 = part[2*(b*8+p)+1];
        float Mn = fmaxf(M, m2);
        S = S*expf(M - Mn) + s2*expf(m2 - Mn);
        M = Mn;
    }
    float lse = M + logf(S);
    int j = blockIdx.x*256 + threadIdx.x;
    if (j < V) y[(long)b*V + j] -= lse;
}

// =====================================================================================
extern "C" void kernel_launch(void* const* d_in, const int* in_sizes, int n_in,
                              void* d_out, int out_size, void* d_ws, size_t ws_size,
                              hipStream_t stream)
{
    const int*   dec_in  = (const int*)  d_in[0];
    const float* attn_h  = (const float*)d_in[1];
    const float* enc     = (const float*)d_in[2];
    // d_in[3] = mask0 (unused: m_w == valid within the window)
    const int*   lengths = (const int*)  d_in[4];
    const float* h0      = (const float*)d_in[5];
    const float* embed   = (const float*)d_in[6];
    const float* w_ih0   = (const float*)d_in[7];
    const float* w_hh0   = (const float*)d_in[8];
    const float* b_ih0   = (const float*)d_in[9];
    const float* b_hh0   = (const float*)d_in[10];
    const float* w_ih1   = (const float*)d_in[11];
    const float* w_hh1   = (const float*)d_in[12];
    const float* b_ih1   = (const float*)d_in[13];
    const float* b_hh1   = (const float*)d_in[14];
    const float* Wp_w    = (const float*)d_in[15];
    const float* Wp_b    = (const float*)d_in[16];
    const float* Vp_w    = (const float*)d_in[17];
    const float* Vp_b    = (const float*)d_in[18];
    const float* Wc_w    = (const float*)d_in[19];
    const float* Wc_b    = (const float*)d_in[20];
    const float* out_w   = (const float*)d_in[21];
    const float* out_b   = (const float*)d_in[22];
    float* y = (float*)d_out;

    // ---- workspace layout, FLOAT units; NO overlaps (verified sizes) ----
    float* ws = (float*)d_ws;
    short* xhi   = (short*)(ws + 0);        // 41,984 fl -> 42,000
    short* xlo   = (short*)(ws + 42000);
    short* h0hi  = (short*)(ws + 84000);    // 65,536 fl -> 65,600
    short* h0lo  = (short*)(ws + 149600);
    short* x1hi  = (short*)(ws + 215200);   // 32,768 fl -> 32,800
    short* x1lo  = (short*)(ws + 248000);
    short* hthi  = (short*)(ws + 280800);
    short* htlo  = (short*)(ws + 313600);
    short* catbf = (short*)(ws + 346400);   // 65,536 fl -> 65,600
    short* habf  = (short*)(ws + 412000);   // 32,768 fl -> 32,800
    float* ht    = ws + 444800;             // 64,000
    float* PgiL0 = ws + 508800;             // 2*5*96000 = 960,000
    float* PghL0 = ws + 1468800;            // 2*2*96000 = 384,000
    float* PgiL1 = ws + 1852800;            // 2*4*96000 = 768,000
    float* PghL1 = ws + 2620800;            // 384,000
    float* Pwp   = ws + 3004800;            // 8*64,000 = 512,000
    float* Pwc   = ws + 3516800;            // 512,000
    float* part  = ws + 4028800;            // 1,024

    dim3 B256(256);

    // 1. prep
    k_prep<<<dim3((64*1312 + 4*64*512 + 1536 + 1536 + 3072 + 255)/256), B256, 0, stream>>>(
        dec_in, attn_h, embed, h0, xhi, xlo, h0hi, h0lo, x1hi, x1lo, hthi, htlo, habf, catbf);

    // 2. all GEMMs independent of x1 (L0 ih + L0 hh + L1 hh)
    k_gru_mm0<<<dim3(24, 5, 6), B256, 0, stream>>>(
        xhi, xlo, h0hi, h0lo, w_ih0, w_hh0, w_hh1, PgiL0, PghL0, PghL1);

    // 3. gates L0 -> x1
    k_gates<0><<<dim3(125, 2), B256, 0, stream>>>(PgiL0, PghL0, h0, b_ih0, b_hh0, x1hi, x1lo, ht, 5, 2);

    // 4. L1 ih GEMM
    k_gru_ih1<<<dim3(24, 4, 2), B256, 0, stream>>>(x1hi, x1lo, w_ih1, PgiL1);

    // 5. gates L1 -> ht
    k_gates<1><<<dim3(125, 2), B256, 0, stream>>>(PgiL1, PghL1, h0, b_ih1, b_hh1, hthi, htlo, ht, 4, 2);

    // 6. Wp GEMM (split-precision)
    k_nn_split4<<<dim3(16, 8), B256, 0, stream>>>(hthi, htlo, Wp_w, Pwp, 1000, 1024, 1000, 4);

    // 7. attention (+pt) -> catbf
    k_attn<<<dim3(64), B256, 0, stream>>>(enc, ht, Pwp, Wp_b, Vp_w, Vp_b, lengths, catbf);

    // 8. Wc GEMM
    k_nn_split<<<dim3(16, 8), B256, 0, stream>>>(catbf, Wc_w, Pwc, 2000, 2048, 1000, 8);

    // 9. hattn combine
    k_hattn<<<dim3(250), B256, 0, stream>>>(Pwc, Wc_b, habf, 8);

    // 10. output projection
    k_out_mm<<<dim3(786), B256, 0, stream>>>(habf, out_w, out_b, y);

    // 11. log_softmax partials
    k_lse_part<<<dim3(512), B256, 0, stream>>>(y, part);

    // 12. merge + subtract
    k_sub2<<<dim3(197, 64), B256, 0, stream>>>(y, part);
}